// Round 1
// baseline (2085.413 us; speedup 1.0000x reference)
//
#include <hip/hip_runtime.h>
#include <hip/hip_bf16.h>
#include <math.h>

#define BB 2
#define C 128
#define H 64
#define W 64
#define L 4096
#define CR4 32
#define PIX 32   // pixels per block in proj kernel
#define PB 4     // columns per block in attention kernel
#define CICH 16  // c_in chunk in conv kernel

__device__ inline float wave_sum(float v) {
    #pragma unroll
    for (int off = 32; off; off >>= 1) v += __shfl_down(v, off, 64);
    return v;
}
__device__ inline float wave_max(float v) {
    #pragma unroll
    for (int off = 32; off; off >>= 1) v = fmaxf(v, __shfl_down(v, off, 64));
    return v;
}
__device__ inline float leaky(float z) { return (z >= 0.f) ? z : 0.2f * z; }

// ---------------------------------------------------------------------------
// Kernel 1: projections + per-pixel wei/bii/dinv
//  writes: x2g [B][C][L], x1t [B][L][C], weiA/biiA/dinvA [B][L]
// ---------------------------------------------------------------------------
__global__ __launch_bounds__(256) void k_proj(
    const float* __restrict__ x,
    const float* __restrict__ vw, const float* __restrict__ vb,
    const float* __restrict__ qw, const float* __restrict__ qb,
    const float* __restrict__ lw1w, const float* __restrict__ lw1b,
    const float* __restrict__ lw2w, const float* __restrict__ lw2b,
    const float* __restrict__ bi1w, const float* __restrict__ bi1b,
    const float* __restrict__ bi2w, const float* __restrict__ bi2b,
    float* __restrict__ x2g, float* __restrict__ x1t,
    float* __restrict__ weiA, float* __restrict__ biiA, float* __restrict__ dinvA)
{
    const int t = threadIdx.x;
    const int blk = blockIdx.x;              // B * (L/PIX) = 256
    const int b = blk / (L / PIX);
    const int p0 = (blk % (L / PIX)) * PIX;

    __shared__ float xt[C][PIX + 1];
    __shared__ float x2t[C][PIX + 1];
    __shared__ float x1tl[C][PIX + 1];
    __shared__ float red[256];

    const float* xb = x + (size_t)b * C * L;
    for (int idx = t; idx < C * PIX; idx += 256) {
        int c = idx >> 5; int w_ = idx & 31;
        xt[c][w_] = xb[(size_t)c * L + p0 + w_];
    }
    __syncthreads();

    const int pix = t & 31;
    const int g = t >> 5;   // 0..7

    #pragma unroll 1
    for (int i = 0; i < 16; ++i) {
        int co = g * 16 + i;
        float accv = vb[co], accq = qb[co];
        const float* wv_ = vw + co * C;
        const float* wq_ = qw + co * C;
        #pragma unroll 4
        for (int ci = 0; ci < C; ++ci) {
            float xv = xt[ci][pix];
            accv = fmaf(wv_[ci], xv, accv);
            accq = fmaf(wq_[ci], xv, accq);
        }
        x2t[co][pix] = accq;
        x1tl[co][pix] = accv;
        x2g[((size_t)b * C + co) * L + p0 + pix] = accq;
    }
    __syncthreads();

    // transposed write of x1: [B][L][C]
    for (int idx = t; idx < C * PIX; idx += 256) {
        int c = idx & (C - 1); int pp = idx >> 7;
        x1t[((size_t)b * L + p0 + pp) * C + c] = x1tl[c][pp];
    }

    // wei / bii / dinv (8 threads per pixel)
    float pw = 0.f, pb_ = 0.f, pn = 0.f;
    #pragma unroll
    for (int i = 0; i < 4; ++i) {
        int hi = g * 4 + i;
        float hl = lw1b[hi], hb = bi1b[hi];
        const float* w1 = lw1w + hi * C;
        const float* w2 = bi1w + hi * C;
        #pragma unroll 4
        for (int ci = 0; ci < C; ++ci) {
            float xv = x2t[ci][pix];
            hl = fmaf(w1[ci], xv, hl);
            hb = fmaf(w2[ci], xv, hb);
        }
        pw = fmaf(lw2w[hi], leaky(hl), pw);
        pb_ = fmaf(bi2w[hi], leaky(hb), pb_);
    }
    #pragma unroll
    for (int k = 0; k < 16; ++k) {
        float xv = x2t[g * 16 + k][pix];
        pn = fmaf(xv, xv, pn);
    }

    red[t] = pw; __syncthreads();
    if (t < 32) {
        float s = 0.f;
        #pragma unroll
        for (int k = 0; k < 8; ++k) s += red[k * 32 + t];
        weiA[(size_t)b * L + p0 + t] = s + lw2b[0];
    }
    __syncthreads();
    red[t] = pb_; __syncthreads();
    if (t < 32) {
        float s = 0.f;
        #pragma unroll
        for (int k = 0; k < 8; ++k) s += red[k * 32 + t];
        biiA[(size_t)b * L + p0 + t] = s + bi2b[0];
    }
    __syncthreads();
    red[t] = pn; __syncthreads();
    if (t < 32) {
        float s = 0.f;
        #pragma unroll
        for (int k = 0; k < 8; ++k) s += red[k * 32 + t];
        float nrm = sqrtf(s);
        dinvA[(size_t)b * L + p0 + t] = 1.f / fmaxf(nrm, 1e-4f);
    }
}

// ---------------------------------------------------------------------------
// Kernel 2: attention. One block = PB=4 output columns of one batch.
// S columns held in LDS; exact gating/softmax/floor semantics.
// ---------------------------------------------------------------------------
__global__ __launch_bounds__(256) void k_attn(
    const float* __restrict__ x2g, const float* __restrict__ x1t,
    const float* __restrict__ weiA, const float* __restrict__ biiA,
    const float* __restrict__ dinvA,
    float* __restrict__ attn)
{
    const int t = threadIdx.x;
    const int blk = blockIdx.x;               // B * L/PB = 2048
    const int b = blk / (L / PB);
    const int p0 = (blk % (L / PB)) * PB;

    __shared__ float S[PB][L];        // 64 KB
    __shared__ float xq[PB][C];
    __shared__ float redw[PB][4];
    __shared__ float smean[PB], colM[PB], colZi[PB], colw[PB], colb[PB];
    __shared__ float redc[PB][C];

    const float* x2b = x2g + (size_t)b * C * L;

    for (int idx = t; idx < PB * C; idx += 256) {
        int j = idx >> 7; int c = idx & (C - 1);
        xq[j][c] = x2b[(size_t)c * L + p0 + j];
    }
    if (t < PB) {
        colw[t] = weiA[(size_t)b * L + p0 + t];
        colb[t] = biiA[(size_t)b * L + p0 + t];
    }
    __syncthreads();

    // ---- Phase A: S[j][l] = dinv_l * (x2_l . x2_{p0+j}) ----
    float a[PB][16];
    #pragma unroll
    for (int j = 0; j < PB; ++j)
        #pragma unroll
        for (int k = 0; k < 16; ++k) a[j][k] = 0.f;

    for (int ci = 0; ci < C; ++ci) {
        float q0 = xq[0][ci], q1 = xq[1][ci], q2 = xq[2][ci], q3 = xq[3][ci];
        const float* px = x2b + (size_t)ci * L + t;
        #pragma unroll
        for (int k = 0; k < 16; ++k) {
            float xv = px[k << 8];
            a[0][k] = fmaf(q0, xv, a[0][k]);
            a[1][k] = fmaf(q1, xv, a[1][k]);
            a[2][k] = fmaf(q2, xv, a[2][k]);
            a[3][k] = fmaf(q3, xv, a[3][k]);
        }
    }

    float lsum[PB] = {0.f, 0.f, 0.f, 0.f};
    #pragma unroll
    for (int k = 0; k < 16; ++k) {
        int l = t + (k << 8);
        float di = dinvA[(size_t)b * L + l];
        #pragma unroll
        for (int j = 0; j < PB; ++j) {
            float v = a[j][k] * di;
            S[j][l] = v;
            lsum[j] += v;
        }
    }

    const int wv = t >> 6, ln = t & 63;
    #pragma unroll
    for (int j = 0; j < PB; ++j) {
        float s = wave_sum(lsum[j]);
        if (ln == 0) redw[j][wv] = s;
    }
    __syncthreads();
    if (t < PB) {
        float s = redw[t][0] + redw[t][1] + redw[t][2] + redw[t][3];
        smean[t] = s * (1.0f / (float)L);
    }
    __syncthreads();

    // hoist per-column scalars
    float mj[PB], wj[PB], bj[PB];
    #pragma unroll
    for (int j = 0; j < PB; ++j) { mj[j] = smean[j]; wj[j] = colw[j]; bj[j] = colb[j]; }

    // ---- Phase B1: max of v over l ----
    float lmax[PB] = {-1e30f, -1e30f, -1e30f, -1e30f};
    #pragma unroll 1
    for (int k = 0; k < 16; ++k) {
        int l = t + (k << 8);
        #pragma unroll
        for (int j = 0; j < PB; ++j) {
            float s = S[j][l];
            float sp = fmaxf(s - mj[j] * wj[j] + bj[j], 0.f);
            float v = s * sp;
            lmax[j] = fmaxf(lmax[j], v);
        }
    }
    #pragma unroll
    for (int j = 0; j < PB; ++j) {
        float s = wave_max(lmax[j]);
        if (ln == 0) redw[j][wv] = s;
    }
    __syncthreads();
    if (t < PB)
        colM[t] = fmaxf(fmaxf(redw[t][0], redw[t][1]), fmaxf(redw[t][2], redw[t][3]));
    __syncthreads();

    float Mj[PB];
    #pragma unroll
    for (int j = 0; j < PB; ++j) Mj[j] = colM[j];

    // ---- Phase B2: Z = sum exp(v - M) over ALL l (masked entries contribute) --
    float lz[PB] = {0.f, 0.f, 0.f, 0.f};
    #pragma unroll 1
    for (int k = 0; k < 16; ++k) {
        int l = t + (k << 8);
        #pragma unroll
        for (int j = 0; j < PB; ++j) {
            float s = S[j][l];
            float sp = fmaxf(s - mj[j] * wj[j] + bj[j], 0.f);
            float v = s * sp;
            lz[j] += __expf(v - Mj[j]);
        }
    }
    #pragma unroll
    for (int j = 0; j < PB; ++j) {
        float s = wave_sum(lz[j]);
        if (ln == 0) redw[j][wv] = s;
    }
    __syncthreads();
    if (t < PB) {
        float s = redw[t][0] + redw[t][1] + redw[t][2] + redw[t][3];
        colZi[t] = 1.0f / s;
    }
    __syncthreads();

    float Zij[PB];
    #pragma unroll
    for (int j = 0; j < PB; ++j) Zij[j] = colZi[j];

    // ---- Phase C1: overwrite S with final weights w_l ----
    #pragma unroll 1
    for (int k = 0; k < 16; ++k) {
        int l = t + (k << 8);
        #pragma unroll
        for (int j = 0; j < PB; ++j) {
            float s = S[j][l];
            float sp = fmaxf(s - mj[j] * wj[j] + bj[j], 0.f);
            float v = s * sp;
            float p = __expf(v - Mj[j]) * Zij[j];
            float w_ = (sp > 0.f) ? fmaxf(p, 1e-8f) : 1e-8f;
            S[j][l] = w_;
        }
    }
    __syncthreads();

    // ---- Phase C2: out[:,p0+j] = sum_l w_l * x1t[l][:] ----
    const int c = t & (C - 1);
    const int half = t >> 7;
    float o[PB] = {0.f, 0.f, 0.f, 0.f};
    const float* xb1 = x1t + ((size_t)b * L) * C + c;
    const int l0 = half * (L / 2), l1 = l0 + (L / 2);
    #pragma unroll 1
    for (int l = l0; l < l1; ++l) {
        float xv = xb1[(size_t)l * C];
        o[0] = fmaf(S[0][l], xv, o[0]);
        o[1] = fmaf(S[1][l], xv, o[1]);
        o[2] = fmaf(S[2][l], xv, o[2]);
        o[3] = fmaf(S[3][l], xv, o[3]);
    }
    if (half == 1) {
        #pragma unroll
        for (int j = 0; j < PB; ++j) redc[j][c] = o[j];
    }
    __syncthreads();
    if (half == 0) {
        #pragma unroll
        for (int j = 0; j < PB; ++j) {
            float r = o[j] + redc[j][c];
            attn[((size_t)b * C + c) * L + p0 + j] = r;
        }
    }
}

// ---------------------------------------------------------------------------
// Kernel 3: 3x3 SAME conv + bias + leaky + residual
// ---------------------------------------------------------------------------
__global__ __launch_bounds__(256) void k_conv(
    const float* __restrict__ attn, const float* __restrict__ x,
    const float* __restrict__ lw, const float* __restrict__ lb,
    float* __restrict__ out)
{
    const int t = threadIdx.x;
    const int h = blockIdx.x;        // 64
    const int cg = blockIdx.y;       // 32
    const int b = blockIdx.z;        // 2
    const int w = t & 63;
    const int co = cg * 4 + (t >> 6);

    __shared__ float tile[CICH][3][66];

    float acc = lb[co];
    for (int ci0 = 0; ci0 < C; ci0 += CICH) {
        __syncthreads();
        for (int idx = t; idx < CICH * 3 * 66; idx += 256) {
            int ci = idx / 198; int r = idx - ci * 198;
            int kh = r / 66; int ww = r - kh * 66;
            int hh = h + kh - 1; int wwg = ww - 1;
            float v = 0.f;
            if ((unsigned)hh < 64u && (unsigned)wwg < 64u)
                v = attn[((size_t)b * C + ci0 + ci) * L + hh * 64 + wwg];
            tile[ci][kh][ww] = v;
        }
        __syncthreads();
        const float* wp = lw + ((size_t)co * C + ci0) * 9;
        #pragma unroll 1
        for (int ci = 0; ci < CICH; ++ci) {
            const float* wpc = wp + ci * 9;
            #pragma unroll
            for (int kh = 0; kh < 3; ++kh)
                #pragma unroll
                for (int kw = 0; kw < 3; ++kw)
                    acc = fmaf(wpc[kh * 3 + kw], tile[ci][kh][w + kw], acc);
        }
    }
    float y = leaky(acc);
    size_t o = ((size_t)b * C + co) * L + (size_t)h * 64 + w;
    out[o] = y + x[o];
}

// ---------------------------------------------------------------------------
extern "C" void kernel_launch(void* const* d_in, const int* in_sizes, int n_in,
                              void* d_out, int out_size, void* d_ws, size_t ws_size,
                              hipStream_t stream) {
    const float* x     = (const float*)d_in[0];
    const float* vw    = (const float*)d_in[1];
    const float* vb    = (const float*)d_in[2];
    const float* qw    = (const float*)d_in[3];
    const float* qb    = (const float*)d_in[4];
    const float* lw1w  = (const float*)d_in[5];
    const float* lw1b  = (const float*)d_in[6];
    const float* lw2w  = (const float*)d_in[7];
    const float* lw2b  = (const float*)d_in[8];
    const float* bi1w  = (const float*)d_in[9];
    const float* bi1b  = (const float*)d_in[10];
    const float* bi2w  = (const float*)d_in[11];
    const float* bi2b  = (const float*)d_in[12];
    const float* lw    = (const float*)d_in[13];
    const float* lb    = (const float*)d_in[14];
    float* out = (float*)d_out;

    float* x2g  = (float*)d_ws;                 // B*C*L
    float* x1t  = x2g + (size_t)BB * C * L;     // B*L*C
    float* attn = x1t + (size_t)BB * C * L;     // B*C*L
    float* weiA = attn + (size_t)BB * C * L;    // B*L
    float* biiA = weiA + (size_t)BB * L;
    float* dinvA = biiA + (size_t)BB * L;

    hipLaunchKernelGGL(k_proj, dim3(BB * (L / PIX)), dim3(256), 0, stream,
                       x, vw, vb, qw, qb, lw1w, lw1b, lw2w, lw2b,
                       bi1w, bi1b, bi2w, bi2b, x2g, x1t, weiA, biiA, dinvA);

    hipLaunchKernelGGL(k_attn, dim3(BB * (L / PB)), dim3(256), 0, stream,
                       x2g, x1t, weiA, biiA, dinvA, attn);

    hipLaunchKernelGGL(k_conv, dim3(64, 32, BB), dim3(256), 0, stream,
                       attn, x, lw, lb, out);
}

// Round 2
// 312.806 us; speedup vs baseline: 6.6668x; 6.6668x over previous
//
#include <hip/hip_runtime.h>
#include <hip/hip_bf16.h>
#include <math.h>

#define BB 2
#define C 128
#define L 4096
#define CR4 32
#define PIX 32
#define CICH 16

typedef unsigned short ushort_t;
typedef __attribute__((ext_vector_type(8))) short s16x8;   // 8 bf16 (4 VGPR)
typedef __attribute__((ext_vector_type(4))) float f32x4;

__device__ inline float leaky(float z) { return (z >= 0.f) ? z : 0.2f * z; }

__device__ inline unsigned short f2bf(float f) {
    unsigned int u = __builtin_bit_cast(unsigned int, f);
    unsigned int r = (u + 0x7fffu + ((u >> 16) & 1u)) >> 16;
    return (unsigned short)r;
}
__device__ inline float bf2f(unsigned short b) {
    unsigned int u = ((unsigned int)b) << 16;
    return __builtin_bit_cast(float, u);
}
__device__ inline unsigned int pack2bf(float a, float b) {
    return (unsigned int)f2bf(a) | ((unsigned int)f2bf(b) << 16);
}

// ---------------------------------------------------------------------------
// Kernel 1: projections. Writes:
//   x2a [b][l][c] bf16 = x2 * dinv_l   (A-side of QK, dinv folded)
//   x1g [b][c][l] bf16 = x1            (PV A-operand layout)
//   weiA/biiA/scA [b][l] f32           (sc = max(norm,1e-4) = 1/dinv)
// ---------------------------------------------------------------------------
__global__ __launch_bounds__(256) void k_proj(
    const float* __restrict__ x,
    const float* __restrict__ vw, const float* __restrict__ vb,
    const float* __restrict__ qw, const float* __restrict__ qb,
    const float* __restrict__ lw1w, const float* __restrict__ lw1b,
    const float* __restrict__ lw2w, const float* __restrict__ lw2b,
    const float* __restrict__ bi1w, const float* __restrict__ bi1b,
    const float* __restrict__ bi2w, const float* __restrict__ bi2b,
    ushort_t* __restrict__ x2a, ushort_t* __restrict__ x1g,
    float* __restrict__ weiA, float* __restrict__ biiA, float* __restrict__ scA)
{
    const int t = threadIdx.x;
    const int blk = blockIdx.x;              // B * (L/PIX) = 256
    const int b = blk / (L / PIX);
    const int p0 = (blk % (L / PIX)) * PIX;

    __shared__ float xt[C][PIX + 1];
    __shared__ float x2t[C][PIX + 1];
    __shared__ float x1tl[C][PIX + 1];
    __shared__ float red[256];
    __shared__ float dinvsh[PIX];

    const float* xb = x + (size_t)b * C * L;
    for (int idx = t; idx < C * PIX; idx += 256) {
        int c = idx >> 5; int w_ = idx & 31;
        xt[c][w_] = xb[(size_t)c * L + p0 + w_];
    }
    __syncthreads();

    const int pix = t & 31;
    const int g = t >> 5;   // 0..7

    #pragma unroll 1
    for (int i = 0; i < 16; ++i) {
        int co = g * 16 + i;
        float accv = vb[co], accq = qb[co];
        const float* wv_ = vw + co * C;
        const float* wq_ = qw + co * C;
        #pragma unroll 4
        for (int ci = 0; ci < C; ++ci) {
            float xv = xt[ci][pix];
            accv = fmaf(wv_[ci], xv, accv);
            accq = fmaf(wq_[ci], xv, accq);
        }
        x2t[co][pix] = accq;
        x1tl[co][pix] = accv;
    }
    __syncthreads();

    // wei / bii / norm (8 threads per pixel)
    float pw = 0.f, pb_ = 0.f, pn = 0.f;
    #pragma unroll
    for (int i = 0; i < 4; ++i) {
        int hi = g * 4 + i;
        float hl = lw1b[hi], hb = bi1b[hi];
        const float* w1 = lw1w + hi * C;
        const float* w2 = bi1w + hi * C;
        #pragma unroll 4
        for (int ci = 0; ci < C; ++ci) {
            float xv = x2t[ci][pix];
            hl = fmaf(w1[ci], xv, hl);
            hb = fmaf(w2[ci], xv, hb);
        }
        pw = fmaf(lw2w[hi], leaky(hl), pw);
        pb_ = fmaf(bi2w[hi], leaky(hb), pb_);
    }
    #pragma unroll
    for (int k = 0; k < 16; ++k) {
        float xv = x2t[g * 16 + k][pix];
        pn = fmaf(xv, xv, pn);
    }

    red[t] = pw; __syncthreads();
    if (t < 32) {
        float s = 0.f;
        #pragma unroll
        for (int k = 0; k < 8; ++k) s += red[k * 32 + t];
        weiA[(size_t)b * L + p0 + t] = s + lw2b[0];
    }
    __syncthreads();
    red[t] = pb_; __syncthreads();
    if (t < 32) {
        float s = 0.f;
        #pragma unroll
        for (int k = 0; k < 8; ++k) s += red[k * 32 + t];
        biiA[(size_t)b * L + p0 + t] = s + bi2b[0];
    }
    __syncthreads();
    red[t] = pn; __syncthreads();
    if (t < 32) {
        float s = 0.f;
        #pragma unroll
        for (int k = 0; k < 8; ++k) s += red[k * 32 + t];
        float nrm = sqrtf(s);
        float scv = fmaxf(nrm, 1e-4f);
        scA[(size_t)b * L + p0 + t] = scv;
        dinvsh[t] = 1.f / scv;
    }
    __syncthreads();

    // x2a writes (c fastest, bf16, dinv folded)
    #pragma unroll 1
    for (int it = 0; it < 16; ++it) {
        int idx = it * 256 + t; int c = idx & 127; int pp = idx >> 7;
        x2a[((size_t)b * L + p0 + pp) * C + c] = f2bf(x2t[c][pp] * dinvsh[pp]);
    }
    // x1g writes (pix fastest, [c][l] layout)
    #pragma unroll 1
    for (int it = 0; it < 16; ++it) {
        int idx = it * 256 + t; int pp = idx & 31; int c = idx >> 5;
        x1g[((size_t)b * C + c) * L + p0 + pp] = f2bf(x1tl[c][pp]);
    }
}

// ---------------------------------------------------------------------------
// Kernel 2a: partial column sums of x2a  -> cpart[b][8][128]
// ---------------------------------------------------------------------------
__global__ __launch_bounds__(256) void k_cvec(
    const ushort_t* __restrict__ x2a, float* __restrict__ cpart)
{
    const int blk = blockIdx.x;       // 16: b = blk>>3, j = blk&7
    const int b = blk >> 3, j = blk & 7;
    const int t = threadIdx.x;
    const int c = t & 127, hf = t >> 7;
    __shared__ float red[256];
    float s = 0.f;
    const int r0 = j * 512 + hf * 256;
    const ushort_t* base = x2a + ((size_t)b * L + r0) * C + c;
    #pragma unroll 4
    for (int r = 0; r < 256; ++r) s += bf2f(base[(size_t)r * C]);
    red[t] = s;
    __syncthreads();
    if (t < 128) cpart[(b * 8 + j) * 128 + t] = red[t] + red[t + 128];
}

// ---------------------------------------------------------------------------
// Kernel 2b: tA[b][l] = wei_l * (c_b . x2_l) - bii_l
// ---------------------------------------------------------------------------
__global__ __launch_bounds__(256) void k_prep(
    const ushort_t* __restrict__ x2a, const float* __restrict__ cpart,
    const float* __restrict__ scA, const float* __restrict__ weiA,
    const float* __restrict__ biiA, float* __restrict__ tAr)
{
    __shared__ float cb[128];
    const int t = threadIdx.x;
    const int blk = blockIdx.x;       // 32: b = blk>>4, seg = blk&15
    const int b = blk >> 4, seg = blk & 15;
    if (t < 128) {
        float s = 0.f;
        #pragma unroll
        for (int j = 0; j < 8; ++j) s += cpart[(b * 8 + j) * 128 + t];
        cb[t] = s * (1.f / (float)L);
    }
    __syncthreads();
    const int l = seg * 256 + t;
    const s16x8* row = (const s16x8*)(x2a + ((size_t)b * L + l) * C);
    float acc = 0.f;
    #pragma unroll 2
    for (int u = 0; u < 16; ++u) {
        s16x8 v = row[u];
        #pragma unroll
        for (int j = 0; j < 8; ++j)
            acc += cb[u * 8 + j] * bf2f((unsigned short)v[j]);
    }
    float mean = acc * scA[(size_t)b * L + l];
    tAr[(size_t)b * L + l] = weiA[(size_t)b * L + l] * mean - biiA[(size_t)b * L + l];
}

// ---------------------------------------------------------------------------
// Kernel 3: flash attention with gating. Grid 256 = B * (L/64 cols) * 2 rowhalves.
// 4 waves, each wave owns 16 columns. Row tiles of 64, double-buffered
// global_load_lds staging with XOR-swizzled source addresses.
// ---------------------------------------------------------------------------
__global__ __launch_bounds__(256, 1) void k_attn(
    const ushort_t* __restrict__ x2a, const ushort_t* __restrict__ x1g,
    const float* __restrict__ scA, const float* __restrict__ tAr,
    ushort_t* __restrict__ Opb, float* __restrict__ Mp, float* __restrict__ Zp)
{
    __shared__ __align__(16) char smem[73728];
    // A (x2 rows) dbuf: 2 x 16KB at 0 / 16384
    // X1 dbuf:          2 x 16KB at 32768 / 49152
    // P per wave:       4 x 2KB  at 65536

    const int t = threadIdx.x;
    const int w = t >> 6, lane = t & 63, n = lane & 15, g = lane >> 4;
    char* Pw = smem + 65536 + w * 2048;

    const int blk = blockIdx.x;
    const int half = blk & 1;
    const int colt = (blk >> 1) & 63;
    const int b = blk >> 7;
    const int p = colt * 64 + w * 16 + n;
    const size_t bL = (size_t)b * L;

    // B-frags (query side): unscale x2a by sc to get raw x2
    const s16x8* qrow = (const s16x8*)(x2a + (bL + p) * C);
    const float scp = scA[bL + p];
    s16x8 bq[4];
    #pragma unroll
    for (int kk = 0; kk < 4; ++kk) {
        s16x8 raw = qrow[kk * 4 + g];
        s16x8 u;
        #pragma unroll
        for (int j = 0; j < 8; ++j)
            u[j] = (short)f2bf(bf2f((unsigned short)raw[j]) * scp);
        bq[kk] = u;
    }
    const float tq = tAr[bL + p];

    f32x4 Oacc[8];
    #pragma unroll
    for (int ct = 0; ct < 8; ++ct) Oacc[ct] = (f32x4){0.f, 0.f, 0.f, 0.f};
    float Mrun = 0.f, Zrun = 0.f;

    const int l0base = half * 2048;
    const char* x2src = (const char*)(x2a + (bL + l0base) * C);     // tile stride 64*256B
    const char* x1src = (const char*)(x1g + (size_t)b * C * L);     // per-c row stride L*2B

    // --- staging helpers (wave-uniform LDS base + lane*16; swizzled source) ---
    #define STAGE_X2(buf, tile_)                                                         \
        {   const char* sb = x2src + (size_t)(tile_) * 64 * 256;                          \
            _Pragma("unroll")                                                             \
            for (int rr = 0; rr < 4; ++rr) {                                              \
                int slot = rr * 256 + t;                                                  \
                int lrow = slot >> 4, uu = slot & 15;                                     \
                const char* gp = sb + lrow * 256 + (((uu ^ (lrow & 7))) << 4);            \
                char* lp = (buf) + ((rr * 256 + w * 64) << 4);                            \
                __builtin_amdgcn_global_load_lds(                                         \
                    (const __attribute__((address_space(1))) unsigned int*)gp,            \
                    (__attribute__((address_space(3))) unsigned int*)lp, 16, 0, 0);       \
            } }
    #define STAGE_X1(buf, l0_)                                                            \
        {   _Pragma("unroll")                                                             \
            for (int rr = 0; rr < 4; ++rr) {                                              \
                int slot = rr * 256 + t;                                                  \
                int cr = slot >> 3, uu = slot & 7;                                        \
                const char* gp = x1src + ((size_t)cr * L + (l0_) + ((uu ^ (cr & 7)) << 3)) * 2; \
                char* lp = (buf) + ((rr * 256 + w * 64) << 4);                            \
                __builtin_amdgcn_global_load_lds(                                         \
                    (const __attribute__((address_space(1))) unsigned int*)gp,            \
                    (__attribute__((address_space(3))) unsigned int*)lp, 16, 0, 0);       \
            } }

    char* Abuf0 = smem;          char* Abuf1 = smem + 16384;
    char* Xbuf0 = smem + 32768;  char* Xbuf1 = smem + 49152;

    STAGE_X2(Abuf0, 0);
    STAGE_X1(Xbuf0, l0base);
    __syncthreads();

    const int swz = n & 7;

    #pragma unroll 1
    for (int tile = 0; tile < 32; ++tile) {
        char* Ab = (tile & 1) ? Abuf1 : Abuf0;
        char* Xb = (tile & 1) ? Xbuf1 : Xbuf0;
        if (tile + 1 < 32) {
            char* An = (tile & 1) ? Abuf0 : Abuf1;
            char* Xn = (tile & 1) ? Xbuf0 : Xbuf1;
            STAGE_X2(An, tile + 1);
            STAGE_X1(Xn, l0base + (tile + 1) * 64);
        }

        // ---- QK: S[64l][16p] ----
        f32x4 s4[4];
        #pragma unroll
        for (int lt = 0; lt < 4; ++lt) s4[lt] = (f32x4){0.f, 0.f, 0.f, 0.f};
        #pragma unroll
        for (int kk = 0; kk < 4; ++kk) {
            #pragma unroll
            for (int lt = 0; lt < 4; ++lt) {
                const s16x8 a = *(const s16x8*)(Ab + (16 * lt + n) * 256 +
                                                (((4 * kk + g) ^ swz) << 4));
                s4[lt] = __builtin_amdgcn_mfma_f32_16x16x32_bf16(a, bq[kk], s4[lt], 0, 0, 0);
            }
        }

        // ---- gating + online softmax (column p is lane-local!) ----
        float vv[16];
        int um = 0;
        float tmax = 0.f;
        #pragma unroll
        for (int lt = 0; lt < 4; ++lt) {
            #pragma unroll
            for (int r = 0; r < 4; ++r) {
                float s = s4[lt][r];
                float sp = s - tq;
                bool m_ = sp > 0.f;
                float v = m_ ? s * sp : 0.f;
                vv[lt * 4 + r] = v;
                um |= ((int)m_) << (lt * 4 + r);
                tmax = fmaxf(tmax, v);
            }
        }
        tmax = fmaxf(tmax, __shfl_xor(tmax, 16, 64));
        tmax = fmaxf(tmax, __shfl_xor(tmax, 32, 64));
        float Mn = fmaxf(Mrun, tmax);
        float sc_old = __expf(Mrun - Mn);
        Mrun = Mn;
        Zrun *= sc_old;
        #pragma unroll
        for (int ct = 0; ct < 8; ++ct) {
            Oacc[ct][0] *= sc_old; Oacc[ct][1] *= sc_old;
            Oacc[ct][2] *= sc_old; Oacc[ct][3] *= sc_old;
        }
        // P = exp(v - M) (masked contribute to Z but write 0 to P)
        #pragma unroll
        for (int lt = 0; lt < 4; ++lt) {
            float e0 = __expf(vv[lt * 4 + 0] - Mn);
            float e1 = __expf(vv[lt * 4 + 1] - Mn);
            float e2 = __expf(vv[lt * 4 + 2] - Mn);
            float e3 = __expf(vv[lt * 4 + 3] - Mn);
            Zrun += (e0 + e1) + (e2 + e3);
            float p0 = ((um >> (lt * 4 + 0)) & 1) ? e0 : 0.f;
            float p1 = ((um >> (lt * 4 + 1)) & 1) ? e1 : 0.f;
            float p2 = ((um >> (lt * 4 + 2)) & 1) ? e2 : 0.f;
            float p3 = ((um >> (lt * 4 + 3)) & 1) ? e3 : 0.f;
            int ulog = 2 * lt + (g >> 1);
            int byte = n * 128 + ((ulog ^ swz) << 4) + ((g & 1) << 3);
            *(unsigned int*)(Pw + byte)     = pack2bf(p0, p1);
            *(unsigned int*)(Pw + byte + 4) = pack2bf(p2, p3);
        }

        // ---- PV: O[128c][16p] += X1^T . P ----
        #pragma unroll
        for (int kk2 = 0; kk2 < 2; ++kk2) {
            const s16x8 pb = *(const s16x8*)(Pw + n * 128 + (((4 * kk2 + g) ^ swz) << 4));
            #pragma unroll
            for (int ct = 0; ct < 8; ++ct) {
                const s16x8 a = *(const s16x8*)(Xb + (16 * ct + n) * 128 +
                                                (((4 * kk2 + g) ^ swz) << 4));
                Oacc[ct] = __builtin_amdgcn_mfma_f32_16x16x32_bf16(a, pb, Oacc[ct], 0, 0, 0);
            }
        }
        __syncthreads();
    }

    float z = Zrun;
    z += __shfl_xor(z, 16, 64);
    z += __shfl_xor(z, 32, 64);

    ushort_t* ob = Opb + ((size_t)(half * BB + b) * L + p) * C;
    #pragma unroll
    for (int ct = 0; ct < 8; ++ct) {
        unsigned int w0 = pack2bf(Oacc[ct][0], Oacc[ct][1]);
        unsigned int w1 = pack2bf(Oacc[ct][2], Oacc[ct][3]);
        uint2 uu; uu.x = w0; uu.y = w1;
        *(uint2*)(ob + 16 * ct + 4 * g) = uu;
    }
    if (g == 0) {
        Mp[(size_t)(half * BB + b) * L + p] = Mrun;
        Zp[(size_t)(half * BB + b) * L + p] = z;
    }
    #undef STAGE_X2
    #undef STAGE_X1
}

// ---------------------------------------------------------------------------
// Kernel 4: merge the two row-halves -> attnb[b][p][c] bf16
// ---------------------------------------------------------------------------
__global__ __launch_bounds__(256) void k_merge(
    const ushort_t* __restrict__ Opb, const float* __restrict__ Mp,
    const float* __restrict__ Zp, ushort_t* __restrict__ attnb)
{
    const int idx = blockIdx.x * 256 + threadIdx.x;   // B*L*C/4 = 262144
    const int c4 = idx & 31;
    const int p = (idx >> 5) & 4095;
    const int b = idx >> 17;
    const size_t i0 = (size_t)b * L + p;
    const size_t i1 = (size_t)(BB + b) * L + p;
    float M0 = Mp[i0], M1 = Mp[i1];
    float Z0 = Zp[i0], Z1 = Zp[i1];
    float M = fmaxf(M0, M1);
    float a0 = __expf(M0 - M), a1 = __expf(M1 - M);
    float zi = 1.f / (Z0 * a0 + Z1 * a1);
    a0 *= zi; a1 *= zi;
    const ushort4 o0 = *(const ushort4*)(Opb + i0 * C + c4 * 4);
    const ushort4 o1 = *(const ushort4*)(Opb + i1 * C + c4 * 4);
    ushort4 r;
    r.x = f2bf(bf2f(o0.x) * a0 + bf2f(o1.x) * a1);
    r.y = f2bf(bf2f(o0.y) * a0 + bf2f(o1.y) * a1);
    r.z = f2bf(bf2f(o0.z) * a0 + bf2f(o1.z) * a1);
    r.w = f2bf(bf2f(o0.w) * a0 + bf2f(o1.w) * a1);
    *(ushort4*)(attnb + i0 * C + c4 * 4) = r;
}

// ---------------------------------------------------------------------------
// Kernel 5: 3x3 SAME conv + bias + leaky + residual (attnb is [b][p][c] bf16)
// ---------------------------------------------------------------------------
__global__ __launch_bounds__(256) void k_conv(
    const ushort_t* __restrict__ attnb, const float* __restrict__ x,
    const float* __restrict__ lw, const float* __restrict__ lb,
    float* __restrict__ out)
{
    const int t = threadIdx.x;
    const int h = blockIdx.x;        // 64
    const int cg = blockIdx.y;       // 32
    const int b = blockIdx.z;        // 2
    const int w = t & 63;
    const int co = cg * 4 + (t >> 6);

    __shared__ float tile[CICH][3][66];

    float acc = lb[co];
    for (int ci0 = 0; ci0 < C; ci0 += CICH) {
        __syncthreads();
        #pragma unroll 1
        for (int it = 0; it < 7; ++it) {
            int idx = it * 256 + t;
            if (idx < 8 * 198) {
                int cp = idx & 7; int pp = idx >> 3;      // pp in 0..197
                int kh = pp / 66; int ww = pp - kh * 66;
                int hh = h + kh - 1; int wwg = ww - 1;
                float v0 = 0.f, v1 = 0.f;
                if ((unsigned)hh < 64u && (unsigned)wwg < 64u) {
                    int pi = hh * 64 + wwg;
                    unsigned int uu = *(const unsigned int*)(
                        attnb + ((size_t)b * L + pi) * C + ci0 + cp * 2);
                    v0 = bf2f((unsigned short)(uu & 0xffff));
                    v1 = bf2f((unsigned short)(uu >> 16));
                }
                tile[cp * 2][kh][ww] = v0;
                tile[cp * 2 + 1][kh][ww] = v1;
            }
        }
        __syncthreads();
        const float* wp = lw + ((size_t)co * C + ci0) * 9;
        #pragma unroll 1
        for (int ci = 0; ci < CICH; ++ci) {
            const float* wpc = wp + ci * 9;
            #pragma unroll
            for (int kh = 0; kh < 3; ++kh)
                #pragma unroll
                for (int kw = 0; kw < 3; ++kw)
                    acc = fmaf(wpc[kh * 3 + kw], tile[ci][kh][w + kw], acc);
        }
    }
    float y = leaky(acc);
    size_t o = ((size_t)b * C + co) * L + (size_t)h * 64 + w;
    out[o] = y + x[o];
}

// ---------------------------------------------------------------------------
extern "C" void kernel_launch(void* const* d_in, const int* in_sizes, int n_in,
                              void* d_out, int out_size, void* d_ws, size_t ws_size,
                              hipStream_t stream) {
    const float* x     = (const float*)d_in[0];
    const float* vw    = (const float*)d_in[1];
    const float* vb    = (const float*)d_in[2];
    const float* qw    = (const float*)d_in[3];
    const float* qb    = (const float*)d_in[4];
    const float* lw1w  = (const float*)d_in[5];
    const float* lw1b  = (const float*)d_in[6];
    const float* lw2w  = (const float*)d_in[7];
    const float* lw2b  = (const float*)d_in[8];
    const float* bi1w  = (const float*)d_in[9];
    const float* bi1b  = (const float*)d_in[10];
    const float* bi2w  = (const float*)d_in[11];
    const float* bi2b  = (const float*)d_in[12];
    const float* lw    = (const float*)d_in[13];
    const float* lb    = (const float*)d_in[14];
    float* out = (float*)d_out;

    char* ws = (char*)d_ws;
    ushort_t* x2a  = (ushort_t*)ws;                      // 2 MB (aliased attnb)
    ushort_t* x1g  = (ushort_t*)(ws + 2097152);          // 2 MB
    ushort_t* Opb  = (ushort_t*)(ws + 4194304);          // 4 MB
    float* weiA  = (float*)(ws + 8388608);               // 32 KB each
    float* biiA  = weiA + BB * L;
    float* scA   = biiA + BB * L;
    float* tAr   = scA + BB * L;
    float* Mp    = tAr + BB * L;                         // 2*BB*L
    float* Zp    = Mp + 2 * BB * L;
    float* cpart = Zp + 2 * BB * L;                      // 2*8*128
    ushort_t* attnb = x2a;                               // alias (x2a dead by merge)

    hipLaunchKernelGGL(k_proj, dim3(BB * (L / PIX)), dim3(256), 0, stream,
                       x, vw, vb, qw, qb, lw1w, lw1b, lw2w, lw2b,
                       bi1w, bi1b, bi2w, bi2b, x2a, x1g, weiA, biiA, scA);

    hipLaunchKernelGGL(k_cvec, dim3(BB * 8), dim3(256), 0, stream, x2a, cpart);

    hipLaunchKernelGGL(k_prep, dim3(BB * 16), dim3(256), 0, stream,
                       x2a, cpart, scA, weiA, biiA, tAr);

    hipLaunchKernelGGL(k_attn, dim3(BB * (L / 64) * 2), dim3(256), 0, stream,
                       x2a, x1g, scA, tAr, Opb, Mp, Zp);

    hipLaunchKernelGGL(k_merge, dim3(BB * L * C / 4 / 256), dim3(256), 0, stream,
                       Opb, Mp, Zp, attnb);

    hipLaunchKernelGGL(k_conv, dim3(64, 32, BB), dim3(256), 0, stream,
                       attnb, x, lw, lb, out);
}

// Round 3
// 186.647 us; speedup vs baseline: 11.1730x; 1.6759x over previous
//
#include <hip/hip_runtime.h>
#include <hip/hip_bf16.h>
#include <math.h>

#define BB 2
#define C 128
#define L 4096
#define CR4 32
#define PIX 32

typedef unsigned short ushort_t;
typedef __attribute__((ext_vector_type(8))) short s16x8;   // 8 bf16 (4 VGPR)
typedef __attribute__((ext_vector_type(4))) float f32x4;

__device__ inline float leaky(float z) { return (z >= 0.f) ? z : 0.2f * z; }

__device__ inline unsigned short f2bf(float f) {
    unsigned int u = __builtin_bit_cast(unsigned int, f);
    unsigned int r = (u + 0x7fffu + ((u >> 16) & 1u)) >> 16;
    return (unsigned short)r;
}
__device__ inline float bf2f(unsigned short b) {
    unsigned int u = ((unsigned int)b) << 16;
    return __builtin_bit_cast(float, u);
}
__device__ inline unsigned int pack2bf(float a, float b) {
    return (unsigned int)f2bf(a) | ((unsigned int)f2bf(b) << 16);
}

// ---------------------------------------------------------------------------
// Kernel 1: projections. Writes:
//   x2a [b][l][c] bf16 = x2 * dinv_l   (A-side of QK, dinv folded)
//   x1g [b][c][l] bf16 = x1            (PV A-operand layout)
//   weiA/biiA/scA [b][l] f32           (sc = max(norm,1e-4) = 1/dinv)
// ---------------------------------------------------------------------------
__global__ __launch_bounds__(256) void k_proj(
    const float* __restrict__ x,
    const float* __restrict__ vw, const float* __restrict__ vb,
    const float* __restrict__ qw, const float* __restrict__ qb,
    const float* __restrict__ lw1w, const float* __restrict__ lw1b,
    const float* __restrict__ lw2w, const float* __restrict__ lw2b,
    const float* __restrict__ bi1w, const float* __restrict__ bi1b,
    const float* __restrict__ bi2w, const float* __restrict__ bi2b,
    ushort_t* __restrict__ x2a, ushort_t* __restrict__ x1g,
    float* __restrict__ weiA, float* __restrict__ biiA, float* __restrict__ scA)
{
    const int t = threadIdx.x;
    const int blk = blockIdx.x;              // B * (L/PIX) = 256
    const int b = blk / (L / PIX);
    const int p0 = (blk % (L / PIX)) * PIX;

    __shared__ float xt[C][PIX + 1];
    __shared__ float x2t[C][PIX + 1];
    __shared__ float x1tl[C][PIX + 1];
    __shared__ float red[256];
    __shared__ float dinvsh[PIX];

    const float* xb = x + (size_t)b * C * L;
    for (int idx = t; idx < C * PIX; idx += 256) {
        int c = idx >> 5; int w_ = idx & 31;
        xt[c][w_] = xb[(size_t)c * L + p0 + w_];
    }
    __syncthreads();

    const int pix = t & 31;
    const int g = t >> 5;   // 0..7

    #pragma unroll 1
    for (int i = 0; i < 16; ++i) {
        int co = g * 16 + i;
        float accv = vb[co], accq = qb[co];
        const float* wv_ = vw + co * C;
        const float* wq_ = qw + co * C;
        #pragma unroll 4
        for (int ci = 0; ci < C; ++ci) {
            float xv = xt[ci][pix];
            accv = fmaf(wv_[ci], xv, accv);
            accq = fmaf(wq_[ci], xv, accq);
        }
        x2t[co][pix] = accq;
        x1tl[co][pix] = accv;
    }
    __syncthreads();

    // wei / bii / norm (8 threads per pixel)
    float pw = 0.f, pb_ = 0.f, pn = 0.f;
    #pragma unroll
    for (int i = 0; i < 4; ++i) {
        int hi = g * 4 + i;
        float hl = lw1b[hi], hb = bi1b[hi];
        const float* w1 = lw1w + hi * C;
        const float* w2 = bi1w + hi * C;
        #pragma unroll 4
        for (int ci = 0; ci < C; ++ci) {
            float xv = x2t[ci][pix];
            hl = fmaf(w1[ci], xv, hl);
            hb = fmaf(w2[ci], xv, hb);
        }
        pw = fmaf(lw2w[hi], leaky(hl), pw);
        pb_ = fmaf(bi2w[hi], leaky(hb), pb_);
    }
    #pragma unroll
    for (int k = 0; k < 16; ++k) {
        float xv = x2t[g * 16 + k][pix];
        pn = fmaf(xv, xv, pn);
    }

    red[t] = pw; __syncthreads();
    if (t < 32) {
        float s = 0.f;
        #pragma unroll
        for (int k = 0; k < 8; ++k) s += red[k * 32 + t];
        weiA[(size_t)b * L + p0 + t] = s + lw2b[0];
    }
    __syncthreads();
    red[t] = pb_; __syncthreads();
    if (t < 32) {
        float s = 0.f;
        #pragma unroll
        for (int k = 0; k < 8; ++k) s += red[k * 32 + t];
        biiA[(size_t)b * L + p0 + t] = s + bi2b[0];
    }
    __syncthreads();
    red[t] = pn; __syncthreads();
    if (t < 32) {
        float s = 0.f;
        #pragma unroll
        for (int k = 0; k < 8; ++k) s += red[k * 32 + t];
        float nrm = sqrtf(s);
        float scv = fmaxf(nrm, 1e-4f);
        scA[(size_t)b * L + p0 + t] = scv;
        dinvsh[t] = 1.f / scv;
    }
    __syncthreads();

    // x2a writes (c fastest, bf16, dinv folded)
    #pragma unroll 1
    for (int it = 0; it < 16; ++it) {
        int idx = it * 256 + t; int c = idx & 127; int pp = idx >> 7;
        x2a[((size_t)b * L + p0 + pp) * C + c] = f2bf(x2t[c][pp] * dinvsh[pp]);
    }
    // x1g writes (pix fastest, [c][l] layout)
    #pragma unroll 1
    for (int it = 0; it < 16; ++it) {
        int idx = it * 256 + t; int pp = idx & 31; int c = idx >> 5;
        x1g[((size_t)b * C + c) * L + p0 + pp] = f2bf(x1tl[c][pp]);
    }
}

// ---------------------------------------------------------------------------
// Kernel 2a: partial column sums of x2a  -> cpart[b][8][128]
// ---------------------------------------------------------------------------
__global__ __launch_bounds__(256) void k_cvec(
    const ushort_t* __restrict__ x2a, float* __restrict__ cpart)
{
    const int blk = blockIdx.x;       // 16: b = blk>>3, j = blk&7
    const int b = blk >> 3, j = blk & 7;
    const int t = threadIdx.x;
    const int c = t & 127, hf = t >> 7;
    __shared__ float red[256];
    float s = 0.f;
    const int r0 = j * 512 + hf * 256;
    const ushort_t* base = x2a + ((size_t)b * L + r0) * C + c;
    #pragma unroll 4
    for (int r = 0; r < 256; ++r) s += bf2f(base[(size_t)r * C]);
    red[t] = s;
    __syncthreads();
    if (t < 128) cpart[(b * 8 + j) * 128 + t] = red[t] + red[t + 128];
}

// ---------------------------------------------------------------------------
// Kernel 2b: tA[b][l] = wei_l * (c_b . x2_l) - bii_l
// ---------------------------------------------------------------------------
__global__ __launch_bounds__(256) void k_prep(
    const ushort_t* __restrict__ x2a, const float* __restrict__ cpart,
    const float* __restrict__ scA, const float* __restrict__ weiA,
    const float* __restrict__ biiA, float* __restrict__ tAr)
{
    __shared__ float cb[128];
    const int t = threadIdx.x;
    const int blk = blockIdx.x;       // 32: b = blk>>4, seg = blk&15
    const int b = blk >> 4, seg = blk & 15;
    if (t < 128) {
        float s = 0.f;
        #pragma unroll
        for (int j = 0; j < 8; ++j) s += cpart[(b * 8 + j) * 128 + t];
        cb[t] = s * (1.f / (float)L);
    }
    __syncthreads();
    const int l = seg * 256 + t;
    const s16x8* row = (const s16x8*)(x2a + ((size_t)b * L + l) * C);
    float acc = 0.f;
    #pragma unroll 2
    for (int u = 0; u < 16; ++u) {
        s16x8 v = row[u];
        #pragma unroll
        for (int j = 0; j < 8; ++j)
            acc += cb[u * 8 + j] * bf2f((unsigned short)v[j]);
    }
    float mean = acc * scA[(size_t)b * L + l];
    tAr[(size_t)b * L + l] = weiA[(size_t)b * L + l] * mean - biiA[(size_t)b * L + l];
}

// ---------------------------------------------------------------------------
// Kernel 3: flash attention with gating. Grid 256 = B * (L/64 cols) * 2 rowhalves.
// ---------------------------------------------------------------------------
__global__ __launch_bounds__(256, 1) void k_attn(
    const ushort_t* __restrict__ x2a, const ushort_t* __restrict__ x1g,
    const float* __restrict__ scA, const float* __restrict__ tAr,
    ushort_t* __restrict__ Opb, float* __restrict__ Mp, float* __restrict__ Zp)
{
    __shared__ __align__(16) char smem[73728];
    // A (x2 rows) dbuf: 2 x 16KB at 0 / 16384
    // X1 dbuf:          2 x 16KB at 32768 / 49152
    // P per wave:       4 x 2KB  at 65536

    const int t = threadIdx.x;
    const int w = t >> 6, lane = t & 63, n = lane & 15, g = lane >> 4;
    char* Pw = smem + 65536 + w * 2048;

    const int blk = blockIdx.x;
    const int half = blk & 1;
    const int colt = (blk >> 1) & 63;
    const int b = blk >> 7;
    const int p = colt * 64 + w * 16 + n;
    const size_t bL = (size_t)b * L;

    // B-frags (query side): unscale x2a by sc to get raw x2
    const s16x8* qrow = (const s16x8*)(x2a + (bL + p) * C);
    const float scp = scA[bL + p];
    s16x8 bq[4];
    #pragma unroll
    for (int kk = 0; kk < 4; ++kk) {
        s16x8 raw = qrow[kk * 4 + g];
        s16x8 u;
        #pragma unroll
        for (int j = 0; j < 8; ++j)
            u[j] = (short)f2bf(bf2f((unsigned short)raw[j]) * scp);
        bq[kk] = u;
    }
    const float tq = tAr[bL + p];

    f32x4 Oacc[8];
    #pragma unroll
    for (int ct = 0; ct < 8; ++ct) Oacc[ct] = (f32x4){0.f, 0.f, 0.f, 0.f};
    float Mrun = 0.f, Zrun = 0.f;

    const int l0base = half * 2048;
    const char* x2src = (const char*)(x2a + (bL + l0base) * C);     // tile stride 64*256B
    const char* x1src = (const char*)(x1g + (size_t)b * C * L);     // per-c row stride L*2B

    #define STAGE_X2(buf, tile_)                                                         \
        {   const char* sb = x2src + (size_t)(tile_) * 64 * 256;                          \
            _Pragma("unroll")                                                             \
            for (int rr = 0; rr < 4; ++rr) {                                              \
                int slot = rr * 256 + t;                                                  \
                int lrow = slot >> 4, uu = slot & 15;                                     \
                const char* gp = sb + lrow * 256 + (((uu ^ (lrow & 7))) << 4);            \
                char* lp = (buf) + ((rr * 256 + w * 64) << 4);                            \
                __builtin_amdgcn_global_load_lds(                                         \
                    (const __attribute__((address_space(1))) unsigned int*)gp,            \
                    (__attribute__((address_space(3))) unsigned int*)lp, 16, 0, 0);       \
            } }
    #define STAGE_X1(buf, l0_)                                                            \
        {   _Pragma("unroll")                                                             \
            for (int rr = 0; rr < 4; ++rr) {                                              \
                int slot = rr * 256 + t;                                                  \
                int cr = slot >> 3, uu = slot & 7;                                        \
                const char* gp = x1src + ((size_t)cr * L + (l0_) + ((uu ^ (cr & 7)) << 3)) * 2; \
                char* lp = (buf) + ((rr * 256 + w * 64) << 4);                            \
                __builtin_amdgcn_global_load_lds(                                         \
                    (const __attribute__((address_space(1))) unsigned int*)gp,            \
                    (__attribute__((address_space(3))) unsigned int*)lp, 16, 0, 0);       \
            } }

    char* Abuf0 = smem;          char* Abuf1 = smem + 16384;
    char* Xbuf0 = smem + 32768;  char* Xbuf1 = smem + 49152;

    STAGE_X2(Abuf0, 0);
    STAGE_X1(Xbuf0, l0base);
    __syncthreads();

    const int swz = n & 7;

    #pragma unroll 1
    for (int tile = 0; tile < 32; ++tile) {
        char* Ab = (tile & 1) ? Abuf1 : Abuf0;
        char* Xb = (tile & 1) ? Xbuf1 : Xbuf0;
        if (tile + 1 < 32) {
            char* An = (tile & 1) ? Abuf0 : Abuf1;
            char* Xn = (tile & 1) ? Xbuf0 : Xbuf1;
            STAGE_X2(An, tile + 1);
            STAGE_X1(Xn, l0base + (tile + 1) * 64);
        }

        // ---- QK: S[64l][16p] ----
        f32x4 s4[4];
        #pragma unroll
        for (int lt = 0; lt < 4; ++lt) s4[lt] = (f32x4){0.f, 0.f, 0.f, 0.f};
        #pragma unroll
        for (int kk = 0; kk < 4; ++kk) {
            #pragma unroll
            for (int lt = 0; lt < 4; ++lt) {
                const s16x8 a = *(const s16x8*)(Ab + (16 * lt + n) * 256 +
                                                (((4 * kk + g) ^ swz) << 4));
                s4[lt] = __builtin_amdgcn_mfma_f32_16x16x32_bf16(a, bq[kk], s4[lt], 0, 0, 0);
            }
        }

        // ---- gating + online softmax (column p is lane-local!) ----
        float vv[16];
        int um = 0;
        float tmax = 0.f;
        #pragma unroll
        for (int lt = 0; lt < 4; ++lt) {
            #pragma unroll
            for (int r = 0; r < 4; ++r) {
                float s = s4[lt][r];
                float sp = s - tq;
                bool m_ = sp > 0.f;
                float v = m_ ? s * sp : 0.f;
                vv[lt * 4 + r] = v;
                um |= ((int)m_) << (lt * 4 + r);
                tmax = fmaxf(tmax, v);
            }
        }
        tmax = fmaxf(tmax, __shfl_xor(tmax, 16, 64));
        tmax = fmaxf(tmax, __shfl_xor(tmax, 32, 64));
        float Mn = fmaxf(Mrun, tmax);
        float sc_old = __expf(Mrun - Mn);
        Mrun = Mn;
        Zrun *= sc_old;
        #pragma unroll
        for (int ct = 0; ct < 8; ++ct) {
            Oacc[ct][0] *= sc_old; Oacc[ct][1] *= sc_old;
            Oacc[ct][2] *= sc_old; Oacc[ct][3] *= sc_old;
        }
        #pragma unroll
        for (int lt = 0; lt < 4; ++lt) {
            float e0 = __expf(vv[lt * 4 + 0] - Mn);
            float e1 = __expf(vv[lt * 4 + 1] - Mn);
            float e2 = __expf(vv[lt * 4 + 2] - Mn);
            float e3 = __expf(vv[lt * 4 + 3] - Mn);
            Zrun += (e0 + e1) + (e2 + e3);
            float p0 = ((um >> (lt * 4 + 0)) & 1) ? e0 : 0.f;
            float p1 = ((um >> (lt * 4 + 1)) & 1) ? e1 : 0.f;
            float p2 = ((um >> (lt * 4 + 2)) & 1) ? e2 : 0.f;
            float p3 = ((um >> (lt * 4 + 3)) & 1) ? e3 : 0.f;
            int ulog = 2 * lt + (g >> 1);
            int byte = n * 128 + ((ulog ^ swz) << 4) + ((g & 1) << 3);
            *(unsigned int*)(Pw + byte)     = pack2bf(p0, p1);
            *(unsigned int*)(Pw + byte + 4) = pack2bf(p2, p3);
        }

        // ---- PV: O[128c][16p] += X1^T . P ----
        #pragma unroll
        for (int kk2 = 0; kk2 < 2; ++kk2) {
            const s16x8 pb = *(const s16x8*)(Pw + n * 128 + (((4 * kk2 + g) ^ swz) << 4));
            #pragma unroll
            for (int ct = 0; ct < 8; ++ct) {
                const s16x8 a = *(const s16x8*)(Xb + (16 * ct + n) * 128 +
                                                (((4 * kk2 + g) ^ swz) << 4));
                Oacc[ct] = __builtin_amdgcn_mfma_f32_16x16x32_bf16(a, pb, Oacc[ct], 0, 0, 0);
            }
        }
        __syncthreads();
    }

    float z = Zrun;
    z += __shfl_xor(z, 16, 64);
    z += __shfl_xor(z, 32, 64);

    ushort_t* ob = Opb + ((size_t)(half * BB + b) * L + p) * C;
    #pragma unroll
    for (int ct = 0; ct < 8; ++ct) {
        unsigned int w0 = pack2bf(Oacc[ct][0], Oacc[ct][1]);
        unsigned int w1 = pack2bf(Oacc[ct][2], Oacc[ct][3]);
        uint2 uu; uu.x = w0; uu.y = w1;
        *(uint2*)(ob + 16 * ct + 4 * g) = uu;
    }
    if (g == 0) {
        Mp[(size_t)(half * BB + b) * L + p] = Mrun;
        Zp[(size_t)(half * BB + b) * L + p] = z;
    }
    #undef STAGE_X2
    #undef STAGE_X1
}

// ---------------------------------------------------------------------------
// Kernel 4: merge the two row-halves -> attnb[b][p][c] bf16
// ---------------------------------------------------------------------------
__global__ __launch_bounds__(256) void k_merge(
    const ushort_t* __restrict__ Opb, const float* __restrict__ Mp,
    const float* __restrict__ Zp, ushort_t* __restrict__ attnb)
{
    const int idx = blockIdx.x * 256 + threadIdx.x;   // B*L*C/4 = 262144
    const int c4 = idx & 31;
    const int p = (idx >> 5) & 4095;
    const int b = idx >> 17;
    const size_t i0 = (size_t)b * L + p;
    const size_t i1 = (size_t)(BB + b) * L + p;
    float M0 = Mp[i0], M1 = Mp[i1];
    float Z0 = Zp[i0], Z1 = Zp[i1];
    float M = fmaxf(M0, M1);
    float a0 = __expf(M0 - M), a1 = __expf(M1 - M);
    float zi = 1.f / (Z0 * a0 + Z1 * a1);
    a0 *= zi; a1 *= zi;
    const ushort4 o0 = *(const ushort4*)(Opb + i0 * C + c4 * 4);
    const ushort4 o1 = *(const ushort4*)(Opb + i1 * C + c4 * 4);
    ushort4 r;
    r.x = f2bf(bf2f(o0.x) * a0 + bf2f(o1.x) * a1);
    r.y = f2bf(bf2f(o0.y) * a0 + bf2f(o1.y) * a1);
    r.z = f2bf(bf2f(o0.z) * a0 + bf2f(o1.z) * a1);
    r.w = f2bf(bf2f(o0.w) * a0 + bf2f(o1.w) * a1);
    *(ushort4*)(attnb + i0 * C + c4 * 4) = r;
}

// ---------------------------------------------------------------------------
// Kernel 5a: repack conv weights into MFMA fragment order (bf16).
// W3 frag index = ((s*8 + mt)*64 + lane)*8 elems; s=kstep (k0=s*32),
// co = mt*16 + (lane&15), g = lane>>4, k = (s>>2)*128 + (s&3)*32 + g*8 + j
// value = lw[co][ci][kh][kw] with ci = (s&3)*32+g*8+j, kk = s>>2 = kh*3+kw.
// ---------------------------------------------------------------------------
__global__ __launch_bounds__(256) void k_wrep(
    const float* __restrict__ lw, ushort_t* __restrict__ W3)
{
    const int tid = blockIdx.x * 256 + threadIdx.x;   // 72*256 = 18432
    const int s = tid >> 9;
    const int r = tid & 511;
    const int mt = r >> 6, lane = r & 63;
    const int co = mt * 16 + (lane & 15), g = lane >> 4;
    const int kk = s >> 2, kc = s & 3;
    const int ci0 = kc * 32 + g * 8;
    s16x8 v;
    #pragma unroll
    for (int j = 0; j < 8; ++j)
        v[j] = (short)f2bf(lw[((size_t)co * 128 + ci0 + j) * 9 + kk]);
    *(s16x8*)(W3 + (size_t)tid * 8) = v;
}

// ---------------------------------------------------------------------------
// Kernel 5b: 3x3 conv as implicit GEMM with MFMA.
// Block = one (h, b): out[128co][64w]. 4 waves; wave wv owns m-tiles
// {2wv, 2wv+1} (co) x all 4 n-tiles (w). K = 1152 in 36 steps of 32.
// attn halo rows (h-1..h+1) staged once in LDS (XOR-swizzled source),
// weight slices double-buffered via linear global_load_lds.
// ---------------------------------------------------------------------------
__global__ __launch_bounds__(256, 1) void k_conv(
    const ushort_t* __restrict__ attnb, const float* __restrict__ x,
    const ushort_t* __restrict__ W3, const float* __restrict__ lb,
    float* __restrict__ out)
{
    __shared__ __align__(16) char smem[65536];
    char* attnT = smem;                 // 192 rows x 256B = 48 KB
    char* Wb0 = smem + 49152;           // 8 KB
    char* Wb1 = smem + 57344;           // 8 KB

    const int t = threadIdx.x;
    const int wv = t >> 6, lane = t & 63, n = lane & 15, g = lane >> 4;
    const int h = blockIdx.x;
    const int b = blockIdx.y;

    // ---- stage attn halo rows (pixel rows (h-1)*64 .. (h+2)*64) ----
    const char* asrc = (const char*)attnb + ((size_t)b * L + (size_t)(h - 1) * 64) * C * 2;
    #pragma unroll
    for (int rr = 0; rr < 3; ++rr) {
        if ((unsigned)(h - 1 + rr) < 64u) {
            #pragma unroll
            for (int q = 0; q < 4; ++q) {
                int slot = rr * 1024 + q * 256 + t;
                int lrow = slot >> 4, uu = slot & 15;
                const char* gp = asrc + lrow * 256 + ((uu ^ (lrow & 7)) << 4);
                char* lp = attnT + ((rr * 1024 + q * 256 + wv * 64) << 4);
                __builtin_amdgcn_global_load_lds(
                    (const __attribute__((address_space(1))) unsigned int*)gp,
                    (__attribute__((address_space(3))) unsigned int*)lp, 16, 0, 0);
            }
        }
    }
    #define STAGE_W(buf, s_)                                                              \
        {   _Pragma("unroll")                                                             \
            for (int q = 0; q < 2; ++q) {                                                 \
                const char* gp = (const char*)W3 + ((size_t)(s_) * 512 + q * 256 + t) * 16; \
                char* lp = (buf) + ((q * 256 + wv * 64) << 4);                            \
                __builtin_amdgcn_global_load_lds(                                         \
                    (const __attribute__((address_space(1))) unsigned int*)gp,            \
                    (__attribute__((address_space(3))) unsigned int*)lp, 16, 0, 0);       \
            } }

    STAGE_W(Wb0, 0);
    __syncthreads();

    f32x4 acc[2][4];
    #pragma unroll
    for (int mi = 0; mi < 2; ++mi)
        #pragma unroll
        for (int nt = 0; nt < 4; ++nt) acc[mi][nt] = (f32x4){0.f, 0.f, 0.f, 0.f};

    const s16x8 zer = {0, 0, 0, 0, 0, 0, 0, 0};

    #pragma unroll 1
    for (int s = 0; s < 36; ++s) {
        char* Wc = (s & 1) ? Wb1 : Wb0;
        if (s + 1 < 36) {
            char* Wn = (s & 1) ? Wb0 : Wb1;
            STAGE_W(Wn, s + 1);
        }
        const int kk = s >> 2, kc = s & 3;
        const int kh = kk / 3, kw = kk - kh * 3;
        const int dh = kh - 1, dw = kw - 1;
        const bool hval = ((unsigned)(h + dh) < 64u);

        s16x8 af0 = *(const s16x8*)(Wc + (((2 * wv) * 64 + lane) << 4));
        s16x8 af1 = *(const s16x8*)(Wc + (((2 * wv + 1) * 64 + lane) << 4));

        #pragma unroll
        for (int nt = 0; nt < 4; ++nt) {
            int pl = nt * 16 + n;
            int wd = pl + dw;
            bool val = hval && ((unsigned)wd < 64u);
            int wc = wd < 0 ? 0 : (wd > 63 ? 63 : wd);
            int lrow = (dh + 1) * 64 + wc;
            s16x8 bf_ = *(const s16x8*)(attnT + lrow * 256 +
                                        (((kc * 4 + g) ^ (lrow & 7)) << 4));
            if (!val) bf_ = zer;
            acc[0][nt] = __builtin_amdgcn_mfma_f32_16x16x32_bf16(af0, bf_, acc[0][nt], 0, 0, 0);
            acc[1][nt] = __builtin_amdgcn_mfma_f32_16x16x32_bf16(af1, bf_, acc[1][nt], 0, 0, 0);
        }
        __syncthreads();
    }
    #undef STAGE_W

    // ---- epilogue: bias + leaky + residual ----
    const float* xb = x + (size_t)b * C * L + h * 64;
    float* ob = out + (size_t)b * C * L + h * 64;
    #pragma unroll
    for (int mi = 0; mi < 2; ++mi) {
        #pragma unroll
        for (int r = 0; r < 4; ++r) {
            int co = (2 * wv + mi) * 16 + g * 4 + r;
            float bias = lb[co];
            #pragma unroll
            for (int nt = 0; nt < 4; ++nt) {
                int p_ = nt * 16 + n;
                float v = leaky(acc[mi][nt][r] + bias);
                ob[(size_t)co * L + p_] = v + xb[(size_t)co * L + p_];
            }
        }
    }
}

// ---------------------------------------------------------------------------
extern "C" void kernel_launch(void* const* d_in, const int* in_sizes, int n_in,
                              void* d_out, int out_size, void* d_ws, size_t ws_size,
                              hipStream_t stream) {
    const float* x     = (const float*)d_in[0];
    const float* vw    = (const float*)d_in[1];
    const float* vb    = (const float*)d_in[2];
    const float* qw    = (const float*)d_in[3];
    const float* qb    = (const float*)d_in[4];
    const float* lw1w  = (const float*)d_in[5];
    const float* lw1b  = (const float*)d_in[6];
    const float* lw2w  = (const float*)d_in[7];
    const float* lw2b  = (const float*)d_in[8];
    const float* bi1w  = (const float*)d_in[9];
    const float* bi1b  = (const float*)d_in[10];
    const float* bi2w  = (const float*)d_in[11];
    const float* bi2b  = (const float*)d_in[12];
    const float* lw    = (const float*)d_in[13];
    const float* lb    = (const float*)d_in[14];
    float* out = (float*)d_out;

    char* ws = (char*)d_ws;
    ushort_t* x2a  = (ushort_t*)ws;                      // 2 MB (aliased attnb)
    ushort_t* x1g  = (ushort_t*)(ws + 2097152);          // 2 MB
    ushort_t* Opb  = (ushort_t*)(ws + 4194304);          // 4 MB
    float* weiA  = (float*)(ws + 8388608);
    float* biiA  = weiA + BB * L;
    float* scA   = biiA + BB * L;
    float* tAr   = scA + BB * L;
    float* Mp    = tAr + BB * L;                         // 2*BB*L
    float* Zp    = Mp + 2 * BB * L;
    float* cpart = Zp + 2 * BB * L;                      // 2*8*128
    ushort_t* W3 = (ushort_t*)(ws + 8658944);            // 288 KB
    ushort_t* attnb = x2a;                               // alias (x2a dead by merge)

    hipLaunchKernelGGL(k_wrep, dim3(72), dim3(256), 0, stream, lw, W3);

    hipLaunchKernelGGL(k_proj, dim3(BB * (L / PIX)), dim3(256), 0, stream,
                       x, vw, vb, qw, qb, lw1w, lw1b, lw2w, lw2b,
                       bi1w, bi1b, bi2w, bi2b, x2a, x1g, weiA, biiA, scA);

    hipLaunchKernelGGL(k_cvec, dim3(BB * 8), dim3(256), 0, stream, x2a, cpart);

    hipLaunchKernelGGL(k_prep, dim3(BB * 16), dim3(256), 0, stream,
                       x2a, cpart, scA, weiA, biiA, tAr);

    hipLaunchKernelGGL(k_attn, dim3(BB * (L / 64) * 2), dim3(256), 0, stream,
                       x2a, x1g, scA, tAr, Opb, Mp, Zp);

    hipLaunchKernelGGL(k_merge, dim3(BB * L * C / 4 / 256), dim3(256), 0, stream,
                       Opb, Mp, Zp, attnb);

    hipLaunchKernelGGL(k_conv, dim3(64, BB), dim3(256), 0, stream,
                       attnb, x, W3, lb, out);
}

// Round 5
// 140.259 us; speedup vs baseline: 14.8683x; 1.3307x over previous
//
#include <hip/hip_runtime.h>
#include <hip/hip_bf16.h>
#include <math.h>

#define BB 2
#define C 128
#define L 4096
#define CR4 32

typedef unsigned short ushort_t;
typedef __attribute__((ext_vector_type(8))) short s16x8;   // 8 bf16 (4 VGPR)
typedef __attribute__((ext_vector_type(4))) float f32x4;

__device__ inline float leaky(float z) { return (z >= 0.f) ? z : 0.2f * z; }

__device__ inline unsigned short f2bf(float f) {
    unsigned int u = __builtin_bit_cast(unsigned int, f);
    unsigned int r = (u + 0x7fffu + ((u >> 16) & 1u)) >> 16;
    return (unsigned short)r;
}
__device__ inline float bf2f(unsigned short b) {
    unsigned int u = ((unsigned int)b) << 16;
    return __builtin_bit_cast(float, u);
}
__device__ inline unsigned int pack2bf(float a, float b) {
    return (unsigned int)f2bf(a) | ((unsigned int)f2bf(b) << 16);
}

// ---------------------------------------------------------------------------
// Kernel 0a: build stacked/composited projection weight table in MFMA A-frag
// order (bf16) + bias vector.
// Rows: 0..127 value_w | 128..255 query_w | 256..287 lw1w@qw | 288..319 bi1w@qw
// ---------------------------------------------------------------------------
__global__ __launch_bounds__(256) void k_wcomp(
    const float* __restrict__ vw, const float* __restrict__ vb,
    const float* __restrict__ qw, const float* __restrict__ qb,
    const float* __restrict__ lw1w, const float* __restrict__ lw1b,
    const float* __restrict__ bi1w, const float* __restrict__ bi1b,
    ushort_t* __restrict__ WQV, float* __restrict__ biasv)
{
    const int mt = blockIdx.x;            // 0..19
    const int t = threadIdx.x;
    const int kk = t >> 6, lane = t & 63;
    const int row = mt * 16 + (lane & 15);
    const int k0 = kk * 32 + (lane >> 4) * 8;
    s16x8 v;
    if (row < 128) {
        #pragma unroll
        for (int j = 0; j < 8; ++j) v[j] = (short)f2bf(vw[row * 128 + k0 + j]);
    } else if (row < 256) {
        #pragma unroll
        for (int j = 0; j < 8; ++j) v[j] = (short)f2bf(qw[(row - 128) * 128 + k0 + j]);
    } else {
        const float* w1 = (row < 288) ? lw1w + (row - 256) * 128
                                      : bi1w + (row - 288) * 128;
        float acc[8] = {0.f, 0.f, 0.f, 0.f, 0.f, 0.f, 0.f, 0.f};
        #pragma unroll 2
        for (int k = 0; k < 128; ++k) {
            float wv_ = w1[k];
            const float* qr = qw + k * 128 + k0;
            #pragma unroll
            for (int j = 0; j < 8; ++j) acc[j] = fmaf(wv_, qr[j], acc[j]);
        }
        #pragma unroll
        for (int j = 0; j < 8; ++j) v[j] = (short)f2bf(acc[j]);
    }
    *(s16x8*)(WQV + ((size_t)(mt * 4 + kk) * 64 + lane) * 8) = v;

    if (t < 16) {
        int rr = mt * 16 + t;
        float bv;
        if (rr < 128) bv = vb[rr];
        else if (rr < 256) bv = qb[rr - 128];
        else {
            const float* w1 = (rr < 288) ? lw1w + (rr - 256) * 128
                                         : bi1w + (rr - 288) * 128;
            float a = (rr < 288) ? lw1b[rr - 256] : bi1b[rr - 288];
            for (int k = 0; k < 128; ++k) a = fmaf(w1[k], qb[k], a);
            bv = a;
        }
        biasv[rr] = bv;
    }
}

// ---------------------------------------------------------------------------
// Kernel 0b: fused projection GEMM. 128 blocks = B * (L/64). 4 waves; wave wv
// owns pixels p0+wv*16..+15 and all 20 m-tiles. x tile transposed to LDS
// bf16 [64p][128k] with 16-slot XOR swizzle. Epilogue: biases, norm, wei/bii,
// x2a [p][c] (dinv folded), x1g [c][p].
// FIX (R4 bug): biasLDS[256..319] and w2LDS were never initialized with a
// 256-thread block -> read stale LDS -> nondeterministic across replays.
// ---------------------------------------------------------------------------
__global__ __launch_bounds__(256, 1) void k_proj2(
    const float* __restrict__ x, const ushort_t* __restrict__ WQV,
    const float* __restrict__ biasv,
    const float* __restrict__ lw2w, const float* __restrict__ lw2b,
    const float* __restrict__ bi2w, const float* __restrict__ bi2b,
    ushort_t* __restrict__ x2a, ushort_t* __restrict__ x1g,
    float* __restrict__ weiA, float* __restrict__ biiA, float* __restrict__ scA)
{
    __shared__ __align__(16) char smem[16384 + 1536];
    char* xT = smem;
    float* biasLDS = (float*)(smem + 16384);   // 320
    float* w2LDS = biasLDS + 320;              // 64: lw2w | bi2w

    const int t = threadIdx.x;
    const int blk = blockIdx.x;
    const int b = blk >> 6;
    const int p0 = (blk & 63) * 64;
    const int wv = t >> 6, lane = t & 63, n = lane & 15, g = lane >> 4;

    // --- LDS param staging: 256 threads cover 320 biases + 64 w2 entries ---
    biasLDS[t] = biasv[t];
    if (t < 64) {
        biasLDS[256 + t] = biasv[256 + t];
        w2LDS[t] = (t < 32) ? lw2w[t] : bi2w[t - 32];
    }

    // stage x tile: [64p][128c] bf16, slot-swizzled
    const int pl = t & 63, cg = t >> 6;
    const float* xb = x + (size_t)b * C * L + p0 + pl;
    #pragma unroll
    for (int i = 0; i < 16; ++i) {
        int c = cg * 32 + i * 2;
        float v0 = xb[(size_t)c * L];
        float v1 = xb[(size_t)(c + 1) * L];
        int slot = c >> 3;
        int offs = (c * 2) & 15;
        int byte = pl * 256 + (((slot ^ (pl & 15)) << 4) | offs);
        *(unsigned int*)(xT + byte) = pack2bf(v0, v1);
    }
    __syncthreads();

    f32x4 acc[20];
    #pragma unroll
    for (int mt = 0; mt < 20; ++mt) acc[mt] = (f32x4){0.f, 0.f, 0.f, 0.f};

    const int brow = wv * 16 + n;
    #pragma unroll
    for (int kk = 0; kk < 4; ++kk) {
        const s16x8 bfr = *(const s16x8*)(xT + brow * 256 + (((4 * kk + g) ^ n) << 4));
        #pragma unroll
        for (int mt = 0; mt < 20; ++mt) {
            const s16x8 afr = *(const s16x8*)(WQV + ((size_t)(mt * 4 + kk) * 64 + lane) * 8);
            acc[mt] = __builtin_amdgcn_mfma_f32_16x16x32_bf16(afr, bfr, acc[mt], 0, 0, 0);
        }
    }

    // biases
    #pragma unroll
    for (int mt = 0; mt < 20; ++mt) {
        const f32x4 bv = *(const f32x4*)(biasLDS + mt * 16 + g * 4);
        acc[mt][0] += bv[0]; acc[mt][1] += bv[1];
        acc[mt][2] += bv[2]; acc[mt][3] += bv[3];
    }

    const int p = p0 + wv * 16 + n;
    const size_t bL = (size_t)b * L;

    // norm over x2 rows (mt 8..15)
    float pn = 0.f;
    #pragma unroll
    for (int mt = 8; mt < 16; ++mt)
        #pragma unroll
        for (int r = 0; r < 4; ++r) pn = fmaf(acc[mt][r], acc[mt][r], pn);
    pn += __shfl_xor(pn, 16, 64);
    pn += __shfl_xor(pn, 32, 64);
    float scv = fmaxf(sqrtf(pn), 1e-4f);
    float dinv = 1.f / scv;

    // wei / bii partials from hidden tiles
    float pw = 0.f, pbb = 0.f;
    #pragma unroll
    for (int mt = 16; mt < 18; ++mt)
        #pragma unroll
        for (int r = 0; r < 4; ++r)
            pw = fmaf(w2LDS[(mt - 16) * 16 + g * 4 + r], leaky(acc[mt][r]), pw);
    #pragma unroll
    for (int mt = 18; mt < 20; ++mt)
        #pragma unroll
        for (int r = 0; r < 4; ++r)
            pbb = fmaf(w2LDS[32 + (mt - 18) * 16 + g * 4 + r], leaky(acc[mt][r]), pbb);
    pw += __shfl_xor(pw, 16, 64);  pw += __shfl_xor(pw, 32, 64);
    pbb += __shfl_xor(pbb, 16, 64); pbb += __shfl_xor(pbb, 32, 64);

    if (g == 0) {
        weiA[bL + p] = pw + lw2b[0];
        biiA[bL + p] = pbb + bi2b[0];
        scA[bL + p]  = scv;
    }

    // x2a [p][c] bf16, dinv folded
    #pragma unroll
    for (int mt = 8; mt < 16; ++mt) {
        uint2 uu;
        uu.x = pack2bf(acc[mt][0] * dinv, acc[mt][1] * dinv);
        uu.y = pack2bf(acc[mt][2] * dinv, acc[mt][3] * dinv);
        *(uint2*)(x2a + (bL + p) * C + (mt - 8) * 16 + g * 4) = uu;
    }
    // x1g [c][p] bf16
    #pragma unroll
    for (int mt = 0; mt < 8; ++mt)
        #pragma unroll
        for (int r = 0; r < 4; ++r)
            x1g[((size_t)b * C + mt * 16 + g * 4 + r) * L + p] = f2bf(acc[mt][r]);
}

// ---------------------------------------------------------------------------
// Kernel 2a: partial column sums of x2a  -> cpart[b][8][128]
// ---------------------------------------------------------------------------
__global__ __launch_bounds__(256) void k_cvec(
    const ushort_t* __restrict__ x2a, float* __restrict__ cpart)
{
    const int blk = blockIdx.x;       // 16
    const int b = blk >> 3, j = blk & 7;
    const int t = threadIdx.x;
    const int c = t & 127, hf = t >> 7;
    __shared__ float red[256];
    float s = 0.f;
    const int r0 = j * 512 + hf * 256;
    const ushort_t* base = x2a + ((size_t)b * L + r0) * C + c;
    #pragma unroll 4
    for (int r = 0; r < 256; ++r) s += bf2f(base[(size_t)r * C]);
    red[t] = s;
    __syncthreads();
    if (t < 128) cpart[(b * 8 + j) * 128 + t] = red[t] + red[t + 128];
}

// ---------------------------------------------------------------------------
// Kernel 2b: tA[b][l] = wei_l * (c_b . x2_l) - bii_l
// ---------------------------------------------------------------------------
__global__ __launch_bounds__(256) void k_prep(
    const ushort_t* __restrict__ x2a, const float* __restrict__ cpart,
    const float* __restrict__ scA, const float* __restrict__ weiA,
    const float* __restrict__ biiA, float* __restrict__ tAr)
{
    __shared__ float cb[128];
    const int t = threadIdx.x;
    const int blk = blockIdx.x;       // 32
    const int b = blk >> 4, seg = blk & 15;
    if (t < 128) {
        float s = 0.f;
        #pragma unroll
        for (int j = 0; j < 8; ++j) s += cpart[(b * 8 + j) * 128 + t];
        cb[t] = s * (1.f / (float)L);
    }
    __syncthreads();
    const int l = seg * 256 + t;
    const s16x8* row = (const s16x8*)(x2a + ((size_t)b * L + l) * C);
    float acc = 0.f;
    #pragma unroll 2
    for (int u = 0; u < 16; ++u) {
        s16x8 v = row[u];
        #pragma unroll
        for (int j = 0; j < 8; ++j)
            acc += cb[u * 8 + j] * bf2f((unsigned short)v[j]);
    }
    float mean = acc * scA[(size_t)b * L + l];
    tAr[(size_t)b * L + l] = weiA[(size_t)b * L + l] * mean - biiA[(size_t)b * L + l];
}

// ---------------------------------------------------------------------------
// Kernel 3: flash attention with gating. Grid 256 = B * (L/64 cols) * 2 rowhalves.
// ---------------------------------------------------------------------------
__global__ __launch_bounds__(256, 1) void k_attn(
    const ushort_t* __restrict__ x2a, const ushort_t* __restrict__ x1g,
    const float* __restrict__ scA, const float* __restrict__ tAr,
    ushort_t* __restrict__ Opb, float* __restrict__ Mp, float* __restrict__ Zp)
{
    __shared__ __align__(16) char smem[73728];

    const int t = threadIdx.x;
    const int w = t >> 6, lane = t & 63, n = lane & 15, g = lane >> 4;
    char* Pw = smem + 65536 + w * 2048;

    const int blk = blockIdx.x;
    const int half = blk & 1;
    const int colt = (blk >> 1) & 63;
    const int b = blk >> 7;
    const int p = colt * 64 + w * 16 + n;
    const size_t bL = (size_t)b * L;

    const s16x8* qrow = (const s16x8*)(x2a + (bL + p) * C);
    const float scp = scA[bL + p];
    s16x8 bq[4];
    #pragma unroll
    for (int kk = 0; kk < 4; ++kk) {
        s16x8 raw = qrow[kk * 4 + g];
        s16x8 u;
        #pragma unroll
        for (int j = 0; j < 8; ++j)
            u[j] = (short)f2bf(bf2f((unsigned short)raw[j]) * scp);
        bq[kk] = u;
    }
    const float tq = tAr[bL + p];

    f32x4 Oacc[8];
    #pragma unroll
    for (int ct = 0; ct < 8; ++ct) Oacc[ct] = (f32x4){0.f, 0.f, 0.f, 0.f};
    float Mrun = 0.f, Zrun = 0.f;

    const int l0base = half * 2048;
    const char* x2src = (const char*)(x2a + (bL + l0base) * C);
    const char* x1src = (const char*)(x1g + (size_t)b * C * L);

    #define STAGE_X2(buf, tile_)                                                         \
        {   const char* sb = x2src + (size_t)(tile_) * 64 * 256;                          \
            _Pragma("unroll")                                                             \
            for (int rr = 0; rr < 4; ++rr) {                                              \
                int slot = rr * 256 + t;                                                  \
                int lrow = slot >> 4, uu = slot & 15;                                     \
                const char* gp = sb + lrow * 256 + (((uu ^ (lrow & 7))) << 4);            \
                char* lp = (buf) + ((rr * 256 + w * 64) << 4);                            \
                __builtin_amdgcn_global_load_lds(                                         \
                    (const __attribute__((address_space(1))) unsigned int*)gp,            \
                    (__attribute__((address_space(3))) unsigned int*)lp, 16, 0, 0);       \
            } }
    #define STAGE_X1(buf, l0_)                                                            \
        {   _Pragma("unroll")                                                             \
            for (int rr = 0; rr < 4; ++rr) {                                              \
                int slot = rr * 256 + t;                                                  \
                int cr = slot >> 3, uu = slot & 7;                                        \
                const char* gp = x1src + ((size_t)cr * L + (l0_) + ((uu ^ (cr & 7)) << 3)) * 2; \
                char* lp = (buf) + ((rr * 256 + w * 64) << 4);                            \
                __builtin_amdgcn_global_load_lds(                                         \
                    (const __attribute__((address_space(1))) unsigned int*)gp,            \
                    (__attribute__((address_space(3))) unsigned int*)lp, 16, 0, 0);       \
            } }

    char* Abuf0 = smem;          char* Abuf1 = smem + 16384;
    char* Xbuf0 = smem + 32768;  char* Xbuf1 = smem + 49152;

    STAGE_X2(Abuf0, 0);
    STAGE_X1(Xbuf0, l0base);
    __syncthreads();

    const int swz = n & 7;

    #pragma unroll 1
    for (int tile = 0; tile < 32; ++tile) {
        char* Ab = (tile & 1) ? Abuf1 : Abuf0;
        char* Xb = (tile & 1) ? Xbuf1 : Xbuf0;
        if (tile + 1 < 32) {
            char* An = (tile & 1) ? Abuf0 : Abuf1;
            char* Xn = (tile & 1) ? Xbuf0 : Xbuf1;
            STAGE_X2(An, tile + 1);
            STAGE_X1(Xn, l0base + (tile + 1) * 64);
        }

        f32x4 s4[4];
        #pragma unroll
        for (int lt = 0; lt < 4; ++lt) s4[lt] = (f32x4){0.f, 0.f, 0.f, 0.f};
        #pragma unroll
        for (int kk = 0; kk < 4; ++kk) {
            #pragma unroll
            for (int lt = 0; lt < 4; ++lt) {
                const s16x8 a = *(const s16x8*)(Ab + (16 * lt + n) * 256 +
                                                (((4 * kk + g) ^ swz) << 4));
                s4[lt] = __builtin_amdgcn_mfma_f32_16x16x32_bf16(a, bq[kk], s4[lt], 0, 0, 0);
            }
        }

        float vv[16];
        int um = 0;
        float tmax = 0.f;
        #pragma unroll
        for (int lt = 0; lt < 4; ++lt) {
            #pragma unroll
            for (int r = 0; r < 4; ++r) {
                float s = s4[lt][r];
                float sp = s - tq;
                bool m_ = sp > 0.f;
                float v = m_ ? s * sp : 0.f;
                vv[lt * 4 + r] = v;
                um |= ((int)m_) << (lt * 4 + r);
                tmax = fmaxf(tmax, v);
            }
        }
        tmax = fmaxf(tmax, __shfl_xor(tmax, 16, 64));
        tmax = fmaxf(tmax, __shfl_xor(tmax, 32, 64));
        float Mn = fmaxf(Mrun, tmax);
        float sc_old = __expf(Mrun - Mn);
        Mrun = Mn;
        Zrun *= sc_old;
        #pragma unroll
        for (int ct = 0; ct < 8; ++ct) {
            Oacc[ct][0] *= sc_old; Oacc[ct][1] *= sc_old;
            Oacc[ct][2] *= sc_old; Oacc[ct][3] *= sc_old;
        }
        #pragma unroll
        for (int lt = 0; lt < 4; ++lt) {
            float e0 = __expf(vv[lt * 4 + 0] - Mn);
            float e1 = __expf(vv[lt * 4 + 1] - Mn);
            float e2 = __expf(vv[lt * 4 + 2] - Mn);
            float e3 = __expf(vv[lt * 4 + 3] - Mn);
            Zrun += (e0 + e1) + (e2 + e3);
            float p0 = ((um >> (lt * 4 + 0)) & 1) ? e0 : 0.f;
            float p1 = ((um >> (lt * 4 + 1)) & 1) ? e1 : 0.f;
            float p2 = ((um >> (lt * 4 + 2)) & 1) ? e2 : 0.f;
            float p3 = ((um >> (lt * 4 + 3)) & 1) ? e3 : 0.f;
            int ulog = 2 * lt + (g >> 1);
            int byte = n * 128 + ((ulog ^ swz) << 4) + ((g & 1) << 3);
            *(unsigned int*)(Pw + byte)     = pack2bf(p0, p1);
            *(unsigned int*)(Pw + byte + 4) = pack2bf(p2, p3);
        }

        #pragma unroll
        for (int kk2 = 0; kk2 < 2; ++kk2) {
            const s16x8 pb = *(const s16x8*)(Pw + n * 128 + (((4 * kk2 + g) ^ swz) << 4));
            #pragma unroll
            for (int ct = 0; ct < 8; ++ct) {
                const s16x8 a = *(const s16x8*)(Xb + (16 * ct + n) * 128 +
                                                (((4 * kk2 + g) ^ swz) << 4));
                Oacc[ct] = __builtin_amdgcn_mfma_f32_16x16x32_bf16(a, pb, Oacc[ct], 0, 0, 0);
            }
        }
        __syncthreads();
    }

    float z = Zrun;
    z += __shfl_xor(z, 16, 64);
    z += __shfl_xor(z, 32, 64);

    ushort_t* ob = Opb + ((size_t)(half * BB + b) * L + p) * C;
    #pragma unroll
    for (int ct = 0; ct < 8; ++ct) {
        unsigned int w0 = pack2bf(Oacc[ct][0], Oacc[ct][1]);
        unsigned int w1 = pack2bf(Oacc[ct][2], Oacc[ct][3]);
        uint2 uu; uu.x = w0; uu.y = w1;
        *(uint2*)(ob + 16 * ct + 4 * g) = uu;
    }
    if (g == 0) {
        Mp[(size_t)(half * BB + b) * L + p] = Mrun;
        Zp[(size_t)(half * BB + b) * L + p] = z;
    }
    #undef STAGE_X2
    #undef STAGE_X1
}

// ---------------------------------------------------------------------------
// Kernel 4: merge the two row-halves -> attnb[b][p][c] bf16
// ---------------------------------------------------------------------------
__global__ __launch_bounds__(256) void k_merge(
    const ushort_t* __restrict__ Opb, const float* __restrict__ Mp,
    const float* __restrict__ Zp, ushort_t* __restrict__ attnb)
{
    const int idx = blockIdx.x * 256 + threadIdx.x;
    const int c4 = idx & 31;
    const int p = (idx >> 5) & 4095;
    const int b = idx >> 17;
    const size_t i0 = (size_t)b * L + p;
    const size_t i1 = (size_t)(BB + b) * L + p;
    float M0 = Mp[i0], M1 = Mp[i1];
    float Z0 = Zp[i0], Z1 = Zp[i1];
    float M = fmaxf(M0, M1);
    float a0 = __expf(M0 - M), a1 = __expf(M1 - M);
    float zi = 1.f / (Z0 * a0 + Z1 * a1);
    a0 *= zi; a1 *= zi;
    const ushort4 o0 = *(const ushort4*)(Opb + i0 * C + c4 * 4);
    const ushort4 o1 = *(const ushort4*)(Opb + i1 * C + c4 * 4);
    ushort4 r;
    r.x = f2bf(bf2f(o0.x) * a0 + bf2f(o1.x) * a1);
    r.y = f2bf(bf2f(o0.y) * a0 + bf2f(o1.y) * a1);
    r.z = f2bf(bf2f(o0.z) * a0 + bf2f(o1.z) * a1);
    r.w = f2bf(bf2f(o0.w) * a0 + bf2f(o1.w) * a1);
    *(ushort4*)(attnb + i0 * C + c4 * 4) = r;
}

// ---------------------------------------------------------------------------
// Kernel 5a: repack conv weights into MFMA fragment order (bf16).
// ---------------------------------------------------------------------------
__global__ __launch_bounds__(256) void k_wrep(
    const float* __restrict__ lw, ushort_t* __restrict__ W3)
{
    const int tid = blockIdx.x * 256 + threadIdx.x;   // 72*256
    const int s = tid >> 9;
    const int r = tid & 511;
    const int mt = r >> 6, lane = r & 63;
    const int co = mt * 16 + (lane & 15), g = lane >> 4;
    const int kk = s >> 2, kc = s & 3;
    const int ci0 = kc * 32 + g * 8;
    s16x8 v;
    #pragma unroll
    for (int j = 0; j < 8; ++j)
        v[j] = (short)f2bf(lw[((size_t)co * 128 + ci0 + j) * 9 + kk]);
    *(s16x8*)(W3 + (size_t)tid * 8) = v;
}

// ---------------------------------------------------------------------------
// Kernel 5b: 3x3 conv as implicit GEMM with MFMA.
// ---------------------------------------------------------------------------
__global__ __launch_bounds__(256, 1) void k_conv(
    const ushort_t* __restrict__ attnb, const float* __restrict__ x,
    const ushort_t* __restrict__ W3, const float* __restrict__ lb,
    float* __restrict__ out)
{
    __shared__ __align__(16) char smem[65536];
    char* attnT = smem;
    char* Wb0 = smem + 49152;
    char* Wb1 = smem + 57344;

    const int t = threadIdx.x;
    const int wv = t >> 6, lane = t & 63, n = lane & 15, g = lane >> 4;
    const int h = blockIdx.x;
    const int b = blockIdx.y;

    const char* asrc = (const char*)attnb + ((size_t)b * L + (size_t)(h - 1) * 64) * C * 2;
    #pragma unroll
    for (int rr = 0; rr < 3; ++rr) {
        if ((unsigned)(h - 1 + rr) < 64u) {
            #pragma unroll
            for (int q = 0; q < 4; ++q) {
                int slot = rr * 1024 + q * 256 + t;
                int lrow = slot >> 4, uu = slot & 15;
                const char* gp = asrc + lrow * 256 + ((uu ^ (lrow & 7)) << 4);
                char* lp = attnT + ((rr * 1024 + q * 256 + wv * 64) << 4);
                __builtin_amdgcn_global_load_lds(
                    (const __attribute__((address_space(1))) unsigned int*)gp,
                    (__attribute__((address_space(3))) unsigned int*)lp, 16, 0, 0);
            }
        }
    }
    #define STAGE_W(buf, s_)                                                              \
        {   _Pragma("unroll")                                                             \
            for (int q = 0; q < 2; ++q) {                                                 \
                const char* gp = (const char*)W3 + ((size_t)(s_) * 512 + q * 256 + t) * 16; \
                char* lp = (buf) + ((q * 256 + wv * 64) << 4);                            \
                __builtin_amdgcn_global_load_lds(                                         \
                    (const __attribute__((address_space(1))) unsigned int*)gp,            \
                    (__attribute__((address_space(3))) unsigned int*)lp, 16, 0, 0);       \
            } }

    STAGE_W(Wb0, 0);
    __syncthreads();

    f32x4 acc[2][4];
    #pragma unroll
    for (int mi = 0; mi < 2; ++mi)
        #pragma unroll
        for (int nt = 0; nt < 4; ++nt) acc[mi][nt] = (f32x4){0.f, 0.f, 0.f, 0.f};

    const s16x8 zer = {0, 0, 0, 0, 0, 0, 0, 0};

    #pragma unroll 1
    for (int s = 0; s < 36; ++s) {
        char* Wc = (s & 1) ? Wb1 : Wb0;
        if (s + 1 < 36) {
            char* Wn = (s & 1) ? Wb0 : Wb1;
            STAGE_W(Wn, s + 1);
        }
        const int kk = s >> 2, kc = s & 3;
        const int kh = kk / 3, kw = kk - kh * 3;
        const int dh = kh - 1, dw = kw - 1;
        const bool hval = ((unsigned)(h + dh) < 64u);

        s16x8 af0 = *(const s16x8*)(Wc + (((2 * wv) * 64 + lane) << 4));
        s16x8 af1 = *(const s16x8*)(Wc + (((2 * wv + 1) * 64 + lane) << 4));

        #pragma unroll
        for (int nt = 0; nt < 4; ++nt) {
            int pl = nt * 16 + n;
            int wd = pl + dw;
            bool val = hval && ((unsigned)wd < 64u);
            int wc = wd < 0 ? 0 : (wd > 63 ? 63 : wd);
            int lrow = (dh + 1) * 64 + wc;
            s16x8 bf_ = *(const s16x8*)(attnT + lrow * 256 +
                                        (((kc * 4 + g) ^ (lrow & 7)) << 4));
            if (!val) bf_ = zer;
            acc[0][nt] = __builtin_amdgcn_mfma_f32_16x16x32_bf16(af0, bf_, acc[0][nt], 0, 0, 0);
            acc[1][nt] = __builtin_amdgcn_mfma_f32_16x16x32_bf16(af1, bf_, acc[1][nt], 0, 0, 0);
        }
        __syncthreads();
    }
    #undef STAGE_W

    const float* xb = x + (size_t)b * C * L + h * 64;
    float* ob = out + (size_t)b * C * L + h * 64;
    #pragma unroll
    for (int mi = 0; mi < 2; ++mi) {
        #pragma unroll
        for (int r = 0; r < 4; ++r) {
            int co = (2 * wv + mi) * 16 + g * 4 + r;
            float bias = lb[co];
            #pragma unroll
            for (int nt = 0; nt < 4; ++nt) {
                int p_ = nt * 16 + n;
                float v = leaky(acc[mi][nt][r] + bias);
                ob[(size_t)co * L + p_] = v + xb[(size_t)co * L + p_];
            }
        }
    }
}

// ---------------------------------------------------------------------------
extern "C" void kernel_launch(void* const* d_in, const int* in_sizes, int n_in,
                              void* d_out, int out_size, void* d_ws, size_t ws_size,
                              hipStream_t stream) {
    const float* x     = (const float*)d_in[0];
    const float* vw    = (const float*)d_in[1];
    const float* vb    = (const float*)d_in[2];
    const float* qw    = (const float*)d_in[3];
    const float* qb    = (const float*)d_in[4];
    const float* lw1w  = (const float*)d_in[5];
    const float* lw1b  = (const float*)d_in[6];
    const float* lw2w  = (const float*)d_in[7];
    const float* lw2b  = (const float*)d_in[8];
    const float* bi1w  = (const float*)d_in[9];
    const float* bi1b  = (const float*)d_in[10];
    const float* bi2w  = (const float*)d_in[11];
    const float* bi2b  = (const float*)d_in[12];
    const float* lw    = (const float*)d_in[13];
    const float* lb    = (const float*)d_in[14];
    float* out = (float*)d_out;

    char* ws = (char*)d_ws;
    ushort_t* x2a  = (ushort_t*)ws;                      // 2 MB (aliased attnb)
    ushort_t* x1g  = (ushort_t*)(ws + 2097152);          // 2 MB
    ushort_t* Opb  = (ushort_t*)(ws + 4194304);          // 4 MB
    float* weiA  = (float*)(ws + 8388608);
    float* biiA  = weiA + BB * L;
    float* scA   = biiA + BB * L;
    float* tAr   = scA + BB * L;
    float* Mp    = tAr + BB * L;
    float* Zp    = Mp + 2 * BB * L;
    float* cpart = Zp + 2 * BB * L;
    ushort_t* W3 = (ushort_t*)(ws + 8658944);            // 288 KB
    ushort_t* WQV = (ushort_t*)(ws + 8953856);           // 80 KB
    float* biasv = (float*)(ws + 9035776);               // 1280 B
    ushort_t* attnb = x2a;

    hipLaunchKernelGGL(k_wrep, dim3(72), dim3(256), 0, stream, lw, W3);

    hipLaunchKernelGGL(k_wcomp, dim3(20), dim3(256), 0, stream,
                       vw, vb, qw, qb, lw1w, lw1b, bi1w, bi1b, WQV, biasv);

    hipLaunchKernelGGL(k_proj2, dim3(BB * (L / 64)), dim3(256), 0, stream,
                       x, WQV, biasv, lw2w, lw2b, bi2w, bi2b,
                       x2a, x1g, weiA, biiA, scA);

    hipLaunchKernelGGL(k_cvec, dim3(BB * 8), dim3(256), 0, stream, x2a, cpart);

    hipLaunchKernelGGL(k_prep, dim3(BB * 16), dim3(256), 0, stream,
                       x2a, cpart, scA, weiA, biiA, tAr);

    hipLaunchKernelGGL(k_attn, dim3(BB * (L / 64) * 2), dim3(256), 0, stream,
                       x2a, x1g, scA, tAr, Opb, Mp, Zp);

    hipLaunchKernelGGL(k_merge, dim3(BB * L * C / 4 / 256), dim3(256), 0, stream,
                       Opb, Mp, Zp, attnb);

    hipLaunchKernelGGL(k_conv, dim3(64, BB), dim3(256), 0, stream,
                       attnb, x, W3, lb, out);
}

// Round 6
// 126.913 us; speedup vs baseline: 16.4318x; 1.1052x over previous
//
#include <hip/hip_runtime.h>
#include <hip/hip_bf16.h>
#include <math.h>

#define BB 2
#define C 128
#define L 4096
#define CR4 32
#define RS 4          // row-split factor in k_attn

typedef unsigned short ushort_t;
typedef __attribute__((ext_vector_type(8))) short s16x8;   // 8 bf16 (4 VGPR)
typedef __attribute__((ext_vector_type(4))) float f32x4;

__device__ inline float leaky(float z) { return (z >= 0.f) ? z : 0.2f * z; }

__device__ inline unsigned short f2bf(float f) {
    unsigned int u = __builtin_bit_cast(unsigned int, f);
    unsigned int r = (u + 0x7fffu + ((u >> 16) & 1u)) >> 16;
    return (unsigned short)r;
}
__device__ inline float bf2f(unsigned short b) {
    unsigned int u = ((unsigned int)b) << 16;
    return __builtin_bit_cast(float, u);
}
__device__ inline unsigned int pack2bf(float a, float b) {
    return (unsigned int)f2bf(a) | ((unsigned int)f2bf(b) << 16);
}
// single-instruction packed f32->2xbf16 (no builtin on gfx950; guide T12)
__device__ inline unsigned int cvtpk(float lo, float hi) {
    unsigned int r;
    asm("v_cvt_pk_bf16_f32 %0, %1, %2" : "=v"(r) : "v"(lo), "v"(hi));
    return r;
}

// ---------------------------------------------------------------------------
// Kernel 0a: stacked/composited projection weights in MFMA A-frag order + bias
// Rows: 0..127 value_w | 128..255 query_w | 256..287 lw1w@qw | 288..319 bi1w@qw
// ---------------------------------------------------------------------------
__global__ __launch_bounds__(256) void k_wcomp(
    const float* __restrict__ vw, const float* __restrict__ vb,
    const float* __restrict__ qw, const float* __restrict__ qb,
    const float* __restrict__ lw1w, const float* __restrict__ lw1b,
    const float* __restrict__ bi1w, const float* __restrict__ bi1b,
    ushort_t* __restrict__ WQV, float* __restrict__ biasv)
{
    const int mt = blockIdx.x;            // 0..19
    const int t = threadIdx.x;
    const int kk = t >> 6, lane = t & 63;
    const int row = mt * 16 + (lane & 15);
    const int k0 = kk * 32 + (lane >> 4) * 8;
    s16x8 v;
    if (row < 128) {
        #pragma unroll
        for (int j = 0; j < 8; ++j) v[j] = (short)f2bf(vw[row * 128 + k0 + j]);
    } else if (row < 256) {
        #pragma unroll
        for (int j = 0; j < 8; ++j) v[j] = (short)f2bf(qw[(row - 128) * 128 + k0 + j]);
    } else {
        const float* w1 = (row < 288) ? lw1w + (row - 256) * 128
                                      : bi1w + (row - 288) * 128;
        float acc[8] = {0.f, 0.f, 0.f, 0.f, 0.f, 0.f, 0.f, 0.f};
        #pragma unroll 2
        for (int k = 0; k < 128; ++k) {
            float wv_ = w1[k];
            const float* qr = qw + k * 128 + k0;
            #pragma unroll
            for (int j = 0; j < 8; ++j) acc[j] = fmaf(wv_, qr[j], acc[j]);
        }
        #pragma unroll
        for (int j = 0; j < 8; ++j) v[j] = (short)f2bf(acc[j]);
    }
    *(s16x8*)(WQV + ((size_t)(mt * 4 + kk) * 64 + lane) * 8) = v;

    if (t < 16) {
        int rr = mt * 16 + t;
        float bv;
        if (rr < 128) bv = vb[rr];
        else if (rr < 256) bv = qb[rr - 128];
        else {
            const float* w1 = (rr < 288) ? lw1w + (rr - 256) * 128
                                         : bi1w + (rr - 288) * 128;
            float a = (rr < 288) ? lw1b[rr - 256] : bi1b[rr - 288];
            for (int k = 0; k < 128; ++k) a = fmaf(w1[k], qb[k], a);
            bv = a;
        }
        biasv[rr] = bv;
    }
}

// ---------------------------------------------------------------------------
// Kernel 0b: fused projection GEMM (unchanged structure from R5, + cvtpk).
// ---------------------------------------------------------------------------
__global__ __launch_bounds__(256, 1) void k_proj2(
    const float* __restrict__ x, const ushort_t* __restrict__ WQV,
    const float* __restrict__ biasv,
    const float* __restrict__ lw2w, const float* __restrict__ lw2b,
    const float* __restrict__ bi2w, const float* __restrict__ bi2b,
    ushort_t* __restrict__ x2a, ushort_t* __restrict__ x1g,
    float* __restrict__ weiA, float* __restrict__ biiA, float* __restrict__ scA)
{
    __shared__ __align__(16) char smem[16384 + 1536];
    char* xT = smem;
    float* biasLDS = (float*)(smem + 16384);   // 320
    float* w2LDS = biasLDS + 320;              // 64: lw2w | bi2w

    const int t = threadIdx.x;
    const int blk = blockIdx.x;
    const int b = blk >> 6;
    const int p0 = (blk & 63) * 64;
    const int wv = t >> 6, lane = t & 63, n = lane & 15, g = lane >> 4;

    biasLDS[t] = biasv[t];
    if (t < 64) {
        biasLDS[256 + t] = biasv[256 + t];
        w2LDS[t] = (t < 32) ? lw2w[t] : bi2w[t - 32];
    }

    const int pl = t & 63, cg = t >> 6;
    const float* xb = x + (size_t)b * C * L + p0 + pl;
    #pragma unroll
    for (int i = 0; i < 16; ++i) {
        int c = cg * 32 + i * 2;
        float v0 = xb[(size_t)c * L];
        float v1 = xb[(size_t)(c + 1) * L];
        int slot = c >> 3;
        int offs = (c * 2) & 15;
        int byte = pl * 256 + (((slot ^ (pl & 15)) << 4) | offs);
        *(unsigned int*)(xT + byte) = cvtpk(v0, v1);
    }
    __syncthreads();

    f32x4 acc[20];
    #pragma unroll
    for (int mt = 0; mt < 20; ++mt) acc[mt] = (f32x4){0.f, 0.f, 0.f, 0.f};

    const int brow = wv * 16 + n;
    #pragma unroll
    for (int kk = 0; kk < 4; ++kk) {
        const s16x8 bfr = *(const s16x8*)(xT + brow * 256 + (((4 * kk + g) ^ n) << 4));
        #pragma unroll
        for (int mt = 0; mt < 20; ++mt) {
            const s16x8 afr = *(const s16x8*)(WQV + ((size_t)(mt * 4 + kk) * 64 + lane) * 8);
            acc[mt] = __builtin_amdgcn_mfma_f32_16x16x32_bf16(afr, bfr, acc[mt], 0, 0, 0);
        }
    }

    #pragma unroll
    for (int mt = 0; mt < 20; ++mt) {
        const f32x4 bv = *(const f32x4*)(biasLDS + mt * 16 + g * 4);
        acc[mt][0] += bv[0]; acc[mt][1] += bv[1];
        acc[mt][2] += bv[2]; acc[mt][3] += bv[3];
    }

    const int p = p0 + wv * 16 + n;
    const size_t bL = (size_t)b * L;

    float pn = 0.f;
    #pragma unroll
    for (int mt = 8; mt < 16; ++mt)
        #pragma unroll
        for (int r = 0; r < 4; ++r) pn = fmaf(acc[mt][r], acc[mt][r], pn);
    pn += __shfl_xor(pn, 16, 64);
    pn += __shfl_xor(pn, 32, 64);
    float scv = fmaxf(sqrtf(pn), 1e-4f);
    float dinv = 1.f / scv;

    float pw = 0.f, pbb = 0.f;
    #pragma unroll
    for (int mt = 16; mt < 18; ++mt)
        #pragma unroll
        for (int r = 0; r < 4; ++r)
            pw = fmaf(w2LDS[(mt - 16) * 16 + g * 4 + r], leaky(acc[mt][r]), pw);
    #pragma unroll
    for (int mt = 18; mt < 20; ++mt)
        #pragma unroll
        for (int r = 0; r < 4; ++r)
            pbb = fmaf(w2LDS[32 + (mt - 18) * 16 + g * 4 + r], leaky(acc[mt][r]), pbb);
    pw += __shfl_xor(pw, 16, 64);  pw += __shfl_xor(pw, 32, 64);
    pbb += __shfl_xor(pbb, 16, 64); pbb += __shfl_xor(pbb, 32, 64);

    if (g == 0) {
        weiA[bL + p] = pw + lw2b[0];
        biiA[bL + p] = pbb + bi2b[0];
        scA[bL + p]  = scv;
    }

    #pragma unroll
    for (int mt = 8; mt < 16; ++mt) {
        uint2 uu;
        uu.x = cvtpk(acc[mt][0] * dinv, acc[mt][1] * dinv);
        uu.y = cvtpk(acc[mt][2] * dinv, acc[mt][3] * dinv);
        *(uint2*)(x2a + (bL + p) * C + (mt - 8) * 16 + g * 4) = uu;
    }
    #pragma unroll
    for (int mt = 0; mt < 8; ++mt)
        #pragma unroll
        for (int r = 0; r < 4; ++r)
            x1g[((size_t)b * C + mt * 16 + g * 4 + r) * L + p] = f2bf(acc[mt][r]);
}

// ---------------------------------------------------------------------------
// Kernel 2a: partial column sums of x2a  -> cpart[b][8][128]
// ---------------------------------------------------------------------------
__global__ __launch_bounds__(256) void k_cvec(
    const ushort_t* __restrict__ x2a, float* __restrict__ cpart)
{
    const int blk = blockIdx.x;       // 16
    const int b = blk >> 3, j = blk & 7;
    const int t = threadIdx.x;
    const int c = t & 127, hf = t >> 7;
    __shared__ float red[256];
    float s = 0.f;
    const int r0 = j * 512 + hf * 256;
    const ushort_t* base = x2a + ((size_t)b * L + r0) * C + c;
    #pragma unroll 4
    for (int r = 0; r < 256; ++r) s += bf2f(base[(size_t)r * C]);
    red[t] = s;
    __syncthreads();
    if (t < 128) cpart[(b * 8 + j) * 128 + t] = red[t] + red[t + 128];
}

// ---------------------------------------------------------------------------
// Kernel 2b: tA[b][l] = wei_l * (c_b . x2_l) - bii_l
// ---------------------------------------------------------------------------
__global__ __launch_bounds__(256) void k_prep(
    const ushort_t* __restrict__ x2a, const float* __restrict__ cpart,
    const float* __restrict__ scA, const float* __restrict__ weiA,
    const float* __restrict__ biiA, float* __restrict__ tAr)
{
    __shared__ float cb[128];
    const int t = threadIdx.x;
    const int blk = blockIdx.x;       // 32
    const int b = blk >> 4, seg = blk & 15;
    if (t < 128) {
        float s = 0.f;
        #pragma unroll
        for (int j = 0; j < 8; ++j) s += cpart[(b * 8 + j) * 128 + t];
        cb[t] = s * (1.f / (float)L);
    }
    __syncthreads();
    const int l = seg * 256 + t;
    const s16x8* row = (const s16x8*)(x2a + ((size_t)b * L + l) * C);
    float acc = 0.f;
    #pragma unroll 2
    for (int u = 0; u < 16; ++u) {
        s16x8 v = row[u];
        #pragma unroll
        for (int j = 0; j < 8; ++j)
            acc += cb[u * 8 + j] * bf2f((unsigned short)v[j]);
    }
    float mean = acc * scA[(size_t)b * L + l];
    tAr[(size_t)b * L + l] = weiA[(size_t)b * L + l] * mean - biiA[(size_t)b * L + l];
}

// ---------------------------------------------------------------------------
// Kernel 3: flash attention with gating. Grid 512 = B * 64 coltiles * RS=4
// row-quarters -> 2 blocks/CU for latency overlap. 16 tiles per block.
// ---------------------------------------------------------------------------
__global__ __launch_bounds__(256, 1) void k_attn(
    const ushort_t* __restrict__ x2a, const ushort_t* __restrict__ x1g,
    const float* __restrict__ scA, const float* __restrict__ tAr,
    ushort_t* __restrict__ Opb, float* __restrict__ Mp, float* __restrict__ Zp)
{
    __shared__ __align__(16) char smem[73728];

    const int t = threadIdx.x;
    const int w = t >> 6, lane = t & 63, n = lane & 15, g = lane >> 4;
    char* Pw = smem + 65536 + w * 2048;

    const int blk = blockIdx.x;
    const int q = blk & (RS - 1);
    const int colt = (blk >> 2) & 63;
    const int b = blk >> 8;
    const int p = colt * 64 + w * 16 + n;
    const size_t bL = (size_t)b * L;

    const s16x8* qrow = (const s16x8*)(x2a + (bL + p) * C);
    const float scp = scA[bL + p];
    s16x8 bq[4];
    #pragma unroll
    for (int kk = 0; kk < 4; ++kk) {
        s16x8 raw = qrow[kk * 4 + g];
        s16x8 u;
        #pragma unroll
        for (int j = 0; j < 8; ++j)
            u[j] = (short)f2bf(bf2f((unsigned short)raw[j]) * scp);
        bq[kk] = u;
    }
    const float tq = tAr[bL + p];

    f32x4 Oacc[8];
    #pragma unroll
    for (int ct = 0; ct < 8; ++ct) Oacc[ct] = (f32x4){0.f, 0.f, 0.f, 0.f};
    float Mrun = 0.f, Zrun = 0.f;

    const int l0base = q * (L / RS);
    const char* x2src = (const char*)(x2a + (bL + l0base) * C);
    const char* x1src = (const char*)(x1g + (size_t)b * C * L);

    #define STAGE_X2(buf, tile_)                                                         \
        {   const char* sb = x2src + (size_t)(tile_) * 64 * 256;                          \
            _Pragma("unroll")                                                             \
            for (int rr = 0; rr < 4; ++rr) {                                              \
                int slot = rr * 256 + t;                                                  \
                int lrow = slot >> 4, uu = slot & 15;                                     \
                const char* gp = sb + lrow * 256 + (((uu ^ (lrow & 7))) << 4);            \
                char* lp = (buf) + ((rr * 256 + w * 64) << 4);                            \
                __builtin_amdgcn_global_load_lds(                                         \
                    (const __attribute__((address_space(1))) unsigned int*)gp,            \
                    (__attribute__((address_space(3))) unsigned int*)lp, 16, 0, 0);       \
            } }
    #define STAGE_X1(buf, l0_)                                                            \
        {   _Pragma("unroll")                                                             \
            for (int rr = 0; rr < 4; ++rr) {                                              \
                int slot = rr * 256 + t;                                                  \
                int cr = slot >> 3, uu = slot & 7;                                        \
                const char* gp = x1src + ((size_t)cr * L + (l0_) + ((uu ^ (cr & 7)) << 3)) * 2; \
                char* lp = (buf) + ((rr * 256 + w * 64) << 4);                            \
                __builtin_amdgcn_global_load_lds(                                         \
                    (const __attribute__((address_space(1))) unsigned int*)gp,            \
                    (__attribute__((address_space(3))) unsigned int*)lp, 16, 0, 0);       \
            } }

    char* Abuf0 = smem;          char* Abuf1 = smem + 16384;
    char* Xbuf0 = smem + 32768;  char* Xbuf1 = smem + 49152;

    STAGE_X2(Abuf0, 0);
    STAGE_X1(Xbuf0, l0base);
    __syncthreads();

    const int swz = n & 7;
    const int NT = L / RS / 64;   // 16

    #pragma unroll 1
    for (int tile = 0; tile < NT; ++tile) {
        char* Ab = (tile & 1) ? Abuf1 : Abuf0;
        char* Xb = (tile & 1) ? Xbuf1 : Xbuf0;
        if (tile + 1 < NT) {
            char* An = (tile & 1) ? Abuf0 : Abuf1;
            char* Xn = (tile & 1) ? Xbuf0 : Xbuf1;
            STAGE_X2(An, tile + 1);
            STAGE_X1(Xn, l0base + (tile + 1) * 64);
        }

        // ---- QK ----
        f32x4 s4[4];
        #pragma unroll
        for (int lt = 0; lt < 4; ++lt) s4[lt] = (f32x4){0.f, 0.f, 0.f, 0.f};
        #pragma unroll
        for (int kk = 0; kk < 4; ++kk) {
            #pragma unroll
            for (int lt = 0; lt < 4; ++lt) {
                const s16x8 a = *(const s16x8*)(Ab + (16 * lt + n) * 256 +
                                                (((4 * kk + g) ^ swz) << 4));
                s4[lt] = __builtin_amdgcn_mfma_f32_16x16x32_bf16(a, bq[kk], s4[lt], 0, 0, 0);
            }
        }

        // ---- gating (branch-free) ----
        float vv[16], sps[16];
        #pragma unroll
        for (int lt = 0; lt < 4; ++lt) {
            #pragma unroll
            for (int r = 0; r < 4; ++r) {
                float s = s4[lt][r];
                float sp = s - tq;
                sps[lt * 4 + r] = sp;
                vv[lt * 4 + r] = s * fmaxf(sp, 0.f);
            }
        }
        // tree max (depth 4)
        float tm[8];
        #pragma unroll
        for (int i = 0; i < 8; ++i) tm[i] = fmaxf(vv[2 * i], vv[2 * i + 1]);
        #pragma unroll
        for (int i = 0; i < 4; ++i) tm[i] = fmaxf(tm[2 * i], tm[2 * i + 1]);
        float tmax = fmaxf(fmaxf(tm[0], tm[1]), fmaxf(tm[2], tm[3]));
        tmax = fmaxf(tmax, __shfl_xor(tmax, 16, 64));
        tmax = fmaxf(tmax, __shfl_xor(tmax, 32, 64));

        // defer-max: skip rescale when no lane's max grew (wave-uniform)
        if (!__all(tmax <= Mrun)) {
            float Mn = fmaxf(Mrun, tmax);
            float sc_old = __expf(Mrun - Mn);
            Mrun = Mn;
            Zrun *= sc_old;
            #pragma unroll
            for (int ct = 0; ct < 8; ++ct) {
                Oacc[ct][0] *= sc_old; Oacc[ct][1] *= sc_old;
                Oacc[ct][2] *= sc_old; Oacc[ct][3] *= sc_old;
            }
        }

        #pragma unroll
        for (int lt = 0; lt < 4; ++lt) {
            float e0 = __expf(vv[lt * 4 + 0] - Mrun);
            float e1 = __expf(vv[lt * 4 + 1] - Mrun);
            float e2 = __expf(vv[lt * 4 + 2] - Mrun);
            float e3 = __expf(vv[lt * 4 + 3] - Mrun);
            Zrun += (e0 + e1) + (e2 + e3);
            float p0 = sps[lt * 4 + 0] > 0.f ? e0 : 0.f;
            float p1 = sps[lt * 4 + 1] > 0.f ? e1 : 0.f;
            float p2 = sps[lt * 4 + 2] > 0.f ? e2 : 0.f;
            float p3 = sps[lt * 4 + 3] > 0.f ? e3 : 0.f;
            int ulog = 2 * lt + (g >> 1);
            int byte = n * 128 + ((ulog ^ swz) << 4) + ((g & 1) << 3);
            uint2 uu;
            uu.x = cvtpk(p0, p1);
            uu.y = cvtpk(p2, p3);
            *(uint2*)(Pw + byte) = uu;
        }

        // ---- PV ----
        #pragma unroll
        for (int kk2 = 0; kk2 < 2; ++kk2) {
            const s16x8 pb = *(const s16x8*)(Pw + n * 128 + (((4 * kk2 + g) ^ swz) << 4));
            #pragma unroll
            for (int ct = 0; ct < 8; ++ct) {
                const s16x8 a = *(const s16x8*)(Xb + (16 * ct + n) * 128 +
                                                (((4 * kk2 + g) ^ swz) << 4));
                Oacc[ct] = __builtin_amdgcn_mfma_f32_16x16x32_bf16(a, pb, Oacc[ct], 0, 0, 0);
            }
        }
        __syncthreads();
    }

    float z = Zrun;
    z += __shfl_xor(z, 16, 64);
    z += __shfl_xor(z, 32, 64);

    const size_t sset = (size_t)(q * BB + b);
    ushort_t* ob = Opb + (sset * L + p) * C;
    #pragma unroll
    for (int ct = 0; ct < 8; ++ct) {
        uint2 uu;
        uu.x = cvtpk(Oacc[ct][0], Oacc[ct][1]);
        uu.y = cvtpk(Oacc[ct][2], Oacc[ct][3]);
        *(uint2*)(ob + 16 * ct + 4 * g) = uu;
    }
    if (g == 0) {
        Mp[sset * L + p] = Mrun;
        Zp[sset * L + p] = z;
    }
    #undef STAGE_X2
    #undef STAGE_X1
}

// ---------------------------------------------------------------------------
// Kernel 4: merge the RS=4 row-quarters -> attnb[b][p][c] bf16
// ---------------------------------------------------------------------------
__global__ __launch_bounds__(256) void k_merge(
    const ushort_t* __restrict__ Opb, const float* __restrict__ Mp,
    const float* __restrict__ Zp, ushort_t* __restrict__ attnb)
{
    const int idx = blockIdx.x * 256 + threadIdx.x;
    const int c4 = idx & 31;
    const int p = (idx >> 5) & 4095;
    const int b = idx >> 17;
    size_t is[RS];
    float M = -1e30f;
    float Mq[RS], Zq[RS];
    #pragma unroll
    for (int q = 0; q < RS; ++q) {
        is[q] = (size_t)(q * BB + b) * L + p;
        Mq[q] = Mp[is[q]];
        Zq[q] = Zp[is[q]];
        M = fmaxf(M, Mq[q]);
    }
    float Zt = 0.f;
    float aq[RS];
    #pragma unroll
    for (int q = 0; q < RS; ++q) {
        aq[q] = __expf(Mq[q] - M);
        Zt = fmaf(Zq[q], aq[q], Zt);
    }
    float zi = 1.f / Zt;
    float r0 = 0.f, r1 = 0.f, r2 = 0.f, r3 = 0.f;
    #pragma unroll
    for (int q = 0; q < RS; ++q) {
        float s = aq[q] * zi;
        const ushort4 o = *(const ushort4*)(Opb + is[q] * C + c4 * 4);
        r0 = fmaf(bf2f(o.x), s, r0);
        r1 = fmaf(bf2f(o.y), s, r1);
        r2 = fmaf(bf2f(o.z), s, r2);
        r3 = fmaf(bf2f(o.w), s, r3);
    }
    uint2 uu;
    uu.x = cvtpk(r0, r1);
    uu.y = cvtpk(r2, r3);
    *(uint2*)(attnb + ((size_t)b * L + p) * C + c4 * 4) = uu;
}

// ---------------------------------------------------------------------------
// Kernel 5a: repack conv weights into MFMA fragment order (bf16).
// NOTE: launched AFTER k_attn — W3 aliases x1g (dead by then).
// ---------------------------------------------------------------------------
__global__ __launch_bounds__(256) void k_wrep(
    const float* __restrict__ lw, ushort_t* __restrict__ W3)
{
    const int tid = blockIdx.x * 256 + threadIdx.x;   // 72*256
    const int s = tid >> 9;
    const int r = tid & 511;
    const int mt = r >> 6, lane = r & 63;
    const int co = mt * 16 + (lane & 15), g = lane >> 4;
    const int kk = s >> 2, kc = s & 3;
    const int ci0 = kc * 32 + g * 8;
    s16x8 v;
    #pragma unroll
    for (int j = 0; j < 8; ++j)
        v[j] = (short)f2bf(lw[((size_t)co * 128 + ci0 + j) * 9 + kk]);
    *(s16x8*)(W3 + (size_t)tid * 8) = v;
}

// ---------------------------------------------------------------------------
// Kernel 5b: 3x3 conv as implicit GEMM with MFMA.
// ---------------------------------------------------------------------------
__global__ __launch_bounds__(256, 1) void k_conv(
    const ushort_t* __restrict__ attnb, const float* __restrict__ x,
    const ushort_t* __restrict__ W3, const float* __restrict__ lb,
    float* __restrict__ out)
{
    __shared__ __align__(16) char smem[65536];
    char* attnT = smem;
    char* Wb0 = smem + 49152;
    char* Wb1 = smem + 57344;

    const int t = threadIdx.x;
    const int wv = t >> 6, lane = t & 63, n = lane & 15, g = lane >> 4;
    const int h = blockIdx.x;
    const int b = blockIdx.y;

    const char* asrc = (const char*)attnb + ((size_t)b * L + (size_t)(h - 1) * 64) * C * 2;
    #pragma unroll
    for (int rr = 0; rr < 3; ++rr) {
        if ((unsigned)(h - 1 + rr) < 64u) {
            #pragma unroll
            for (int qq = 0; qq < 4; ++qq) {
                int slot = rr * 1024 + qq * 256 + t;
                int lrow = slot >> 4, uu = slot & 15;
                const char* gp = asrc + lrow * 256 + ((uu ^ (lrow & 7)) << 4);
                char* lp = attnT + ((rr * 1024 + qq * 256 + wv * 64) << 4);
                __builtin_amdgcn_global_load_lds(
                    (const __attribute__((address_space(1))) unsigned int*)gp,
                    (__attribute__((address_space(3))) unsigned int*)lp, 16, 0, 0);
            }
        }
    }
    #define STAGE_W(buf, s_)                                                              \
        {   _Pragma("unroll")                                                             \
            for (int qq = 0; qq < 2; ++qq) {                                              \
                const char* gp = (const char*)W3 + ((size_t)(s_) * 512 + qq * 256 + t) * 16; \
                char* lp = (buf) + ((qq * 256 + wv * 64) << 4);                           \
                __builtin_amdgcn_global_load_lds(                                         \
                    (const __attribute__((address_space(1))) unsigned int*)gp,            \
                    (__attribute__((address_space(3))) unsigned int*)lp, 16, 0, 0);       \
            } }

    STAGE_W(Wb0, 0);
    __syncthreads();

    f32x4 acc[2][4];
    #pragma unroll
    for (int mi = 0; mi < 2; ++mi)
        #pragma unroll
        for (int nt = 0; nt < 4; ++nt) acc[mi][nt] = (f32x4){0.f, 0.f, 0.f, 0.f};

    const s16x8 zer = {0, 0, 0, 0, 0, 0, 0, 0};

    #pragma unroll 1
    for (int s = 0; s < 36; ++s) {
        char* Wc = (s & 1) ? Wb1 : Wb0;
        if (s + 1 < 36) {
            char* Wn = (s & 1) ? Wb0 : Wb1;
            STAGE_W(Wn, s + 1);
        }
        const int kk = s >> 2, kc = s & 3;
        const int kh = kk / 3, kw = kk - kh * 3;
        const int dh = kh - 1, dw = kw - 1;
        const bool hval = ((unsigned)(h + dh) < 64u);

        s16x8 af0 = *(const s16x8*)(Wc + (((2 * wv) * 64 + lane) << 4));
        s16x8 af1 = *(const s16x8*)(Wc + (((2 * wv + 1) * 64 + lane) << 4));

        #pragma unroll
        for (int nt = 0; nt < 4; ++nt) {
            int pl = nt * 16 + n;
            int wd = pl + dw;
            bool val = hval && ((unsigned)wd < 64u);
            int wc = wd < 0 ? 0 : (wd > 63 ? 63 : wd);
            int lrow = (dh + 1) * 64 + wc;
            s16x8 bf_ = *(const s16x8*)(attnT + lrow * 256 +
                                        (((kc * 4 + g) ^ (lrow & 7)) << 4));
            if (!val) bf_ = zer;
            acc[0][nt] = __builtin_amdgcn_mfma_f32_16x16x32_bf16(af0, bf_, acc[0][nt], 0, 0, 0);
            acc[1][nt] = __builtin_amdgcn_mfma_f32_16x16x32_bf16(af1, bf_, acc[1][nt], 0, 0, 0);
        }
        __syncthreads();
    }
    #undef STAGE_W

    const float* xb = x + (size_t)b * C * L + h * 64;
    float* ob = out + (size_t)b * C * L + h * 64;
    #pragma unroll
    for (int mi = 0; mi < 2; ++mi) {
        #pragma unroll
        for (int r = 0; r < 4; ++r) {
            int co = (2 * wv + mi) * 16 + g * 4 + r;
            float bias = lb[co];
            #pragma unroll
            for (int nt = 0; nt < 4; ++nt) {
                int p_ = nt * 16 + n;
                float v = leaky(acc[mi][nt][r] + bias);
                ob[(size_t)co * L + p_] = v + xb[(size_t)co * L + p_];
            }
        }
    }
}

// ---------------------------------------------------------------------------
extern "C" void kernel_launch(void* const* d_in, const int* in_sizes, int n_in,
                              void* d_out, int out_size, void* d_ws, size_t ws_size,
                              hipStream_t stream) {
    const float* x     = (const float*)d_in[0];
    const float* vw    = (const float*)d_in[1];
    const float* vb    = (const float*)d_in[2];
    const float* qw    = (const float*)d_in[3];
    const float* qb    = (const float*)d_in[4];
    const float* lw1w  = (const float*)d_in[5];
    const float* lw1b  = (const float*)d_in[6];
    const float* lw2w  = (const float*)d_in[7];
    const float* lw2b  = (const float*)d_in[8];
    const float* bi1w  = (const float*)d_in[9];
    const float* bi1b  = (const float*)d_in[10];
    const float* bi2w  = (const float*)d_in[11];
    const float* bi2b  = (const float*)d_in[12];
    const float* lw    = (const float*)d_in[13];
    const float* lb    = (const float*)d_in[14];
    float* out = (float*)d_out;

    char* ws = (char*)d_ws;
    // layout (peak 12.38 MB; aliases keep us under the 12.68 MB proven in R1):
    ushort_t* x2a  = (ushort_t*)ws;                      // 2 MB  (attnb alias)
    ushort_t* x1g  = (ushort_t*)(ws + 2097152);          // 2 MB  (W3 alias, post-attn)
    ushort_t* Opb  = (ushort_t*)(ws + 4194304);          // 8 MB  (RS=4 partials)
    ushort_t* WQV  = (ushort_t*)(ws + 4194304);          // 80 KB, dead before k_attn
    float* biasv = (float*)(ws + 4194304 + 81920);       // 1280 B, dead before k_attn
    float* weiA  = (float*)(ws + 12582912);              // 32 KB each
    float* biiA  = weiA + BB * L;
    float* scA   = biiA + BB * L;
    float* tAr   = scA + BB * L;
    float* Mp    = tAr + BB * L;                         // RS*BB*L
    float* Zp    = Mp + RS * BB * L;                     // RS*BB*L
    float* cpart = Zp + RS * BB * L;                     // 8 KB
    ushort_t* W3 = x1g;                                  // 288 KB (after k_attn)
    ushort_t* attnb = x2a;

    hipLaunchKernelGGL(k_wcomp, dim3(20), dim3(256), 0, stream,
                       vw, vb, qw, qb, lw1w, lw1b, bi1w, bi1b, WQV, biasv);

    hipLaunchKernelGGL(k_proj2, dim3(BB * (L / 64)), dim3(256), 0, stream,
                       x, WQV, biasv, lw2w, lw2b, bi2w, bi2b,
                       x2a, x1g, weiA, biiA, scA);

    hipLaunchKernelGGL(k_cvec, dim3(BB * 8), dim3(256), 0, stream, x2a, cpart);

    hipLaunchKernelGGL(k_prep, dim3(BB * 16), dim3(256), 0, stream,
                       x2a, cpart, scA, weiA, biiA, tAr);

    hipLaunchKernelGGL(k_attn, dim3(BB * 64 * RS), dim3(256), 0, stream,
                       x2a, x1g, scA, tAr, Opb, Mp, Zp);

    hipLaunchKernelGGL(k_wrep, dim3(72), dim3(256), 0, stream, lw, W3);

    hipLaunchKernelGGL(k_merge, dim3(BB * L * C / 4 / 256), dim3(256), 0, stream,
                       Opb, Mp, Zp, attnb);

    hipLaunchKernelGGL(k_conv, dim3(64, BB), dim3(256), 0, stream,
                       attnb, x, W3, lb, out);
}